// Round 4
// baseline (926.271 us; speedup 1.0000x reference)
//
#include <hip/hip_runtime.h>

#define NN 100000
#define NE 1600000
#define NG 1024
#define NBLK_SCAN ((NN + 255) / 256)  // 391

// ------------------------------------------------------------- CSR build ----
__global__ __launch_bounds__(256) void k_count(const int* __restrict__ dst,
                                               int* __restrict__ cnt) {
  int e = blockIdx.x * 256 + threadIdx.x;
  if (e < NE) atomicAdd(&cnt[dst[e]], 1);
}

__global__ __launch_bounds__(256) void k_scan1(const int* __restrict__ cnt,
                                               int* __restrict__ off,
                                               int* __restrict__ bsum) {
  __shared__ int s[256];
  int tid = threadIdx.x;
  int i = blockIdx.x * 256 + tid;
  int v = (i < NN) ? cnt[i] : 0;
  s[tid] = v;
  __syncthreads();
  for (int d = 1; d < 256; d <<= 1) {
    int t = (tid >= d) ? s[tid - d] : 0;
    __syncthreads();
    s[tid] += t;
    __syncthreads();
  }
  if (i < NN) off[i] = s[tid] - v;  // exclusive
  if (tid == 255) bsum[blockIdx.x] = s[255];
}

__global__ __launch_bounds__(512) void k_scan2(int* __restrict__ bsum) {
  __shared__ int s[512];
  int tid = threadIdx.x;
  int v = (tid < NBLK_SCAN) ? bsum[tid] : 0;
  s[tid] = v;
  __syncthreads();
  for (int d = 1; d < 512; d <<= 1) {
    int t = (tid >= d) ? s[tid - d] : 0;
    __syncthreads();
    s[tid] += t;
    __syncthreads();
  }
  if (tid < NBLK_SCAN) bsum[tid] = s[tid] - v;  // exclusive
}

// scan stage 3 + invdeg fused (both are per-node, same grid)
__global__ __launch_bounds__(256) void k_scan3(int* __restrict__ off,
                                               const int* __restrict__ bsum,
                                               int* __restrict__ cursor,
                                               const int* __restrict__ cnt,
                                               float* __restrict__ inv) {
  int i = blockIdx.x * 256 + threadIdx.x;
  if (i < NN) {
    int o = off[i] + bsum[blockIdx.x];
    off[i] = o;
    cursor[i] = o;
    inv[i] = 1.0f / fmaxf((float)cnt[i], 1.0f);
  }
  if (i == 0) off[NN] = NE;
}

__global__ __launch_bounds__(256) void k_fill(const int* __restrict__ src,
                                              const int* __restrict__ dst,
                                              int* __restrict__ cursor,
                                              int* __restrict__ csr) {
  int e = blockIdx.x * 256 + threadIdx.x;
  if (e < NE) {
    int d = dst[e];
    int pos = atomicAdd(&cursor[d], 1);
    csr[pos] = src[e];
  }
}

// graph segment boundaries in the SORTED batch array
__global__ __launch_bounds__(256) void k_bounds(const int* __restrict__ batch,
                                                int* __restrict__ gstart) {
  int g = blockIdx.x * 256 + threadIdx.x;
  if (g > NG) return;
  int lo = 0, hi = NN;
  while (lo < hi) {
    int mid = (lo + hi) >> 1;
    if (batch[mid] < g) lo = mid + 1; else hi = mid;
  }
  gstart[g] = lo;
}

// --------------------------------------------------------- gather-aggregate -
// out[n] = inv[n]*sum_{e}(F[csr[e]])            (bias==null)
// out[n] = relu(inv[n]*sum + bias + Z[n])       (bias!=null, layer-2 epilogue)
__global__ __launch_bounds__(256) void k_gather(const float* __restrict__ F,
                                                const int* __restrict__ csr,
                                                const int* __restrict__ off,
                                                const float* __restrict__ inv,
                                                const float* __restrict__ bias,
                                                const float* __restrict__ Z,
                                                float* __restrict__ out) {
  int idx = blockIdx.x * 256 + threadIdx.x;  // grid = NN*16 threads
  int n = idx >> 4;
  int q = (idx & 15) << 2;
  int beg = off[n], end = off[n + 1];
  float4 a0 = make_float4(0.f, 0.f, 0.f, 0.f);
  float4 a1 = a0, a2 = a0, a3 = a0;
  int e = beg;
  for (; e + 4 <= end; e += 4) {
    int s0 = csr[e], s1 = csr[e + 1], s2 = csr[e + 2], s3 = csr[e + 3];
    const float4 v0 = *reinterpret_cast<const float4*>(&F[(size_t)s0 * 64 + q]);
    const float4 v1 = *reinterpret_cast<const float4*>(&F[(size_t)s1 * 64 + q]);
    const float4 v2 = *reinterpret_cast<const float4*>(&F[(size_t)s2 * 64 + q]);
    const float4 v3 = *reinterpret_cast<const float4*>(&F[(size_t)s3 * 64 + q]);
    a0.x += v0.x; a0.y += v0.y; a0.z += v0.z; a0.w += v0.w;
    a1.x += v1.x; a1.y += v1.y; a1.z += v1.z; a1.w += v1.w;
    a2.x += v2.x; a2.y += v2.y; a2.z += v2.z; a2.w += v2.w;
    a3.x += v3.x; a3.y += v3.y; a3.z += v3.z; a3.w += v3.w;
  }
  for (; e < end; ++e) {
    int s0 = csr[e];
    const float4 v0 = *reinterpret_cast<const float4*>(&F[(size_t)s0 * 64 + q]);
    a0.x += v0.x; a0.y += v0.y; a0.z += v0.z; a0.w += v0.w;
  }
  float4 acc;
  acc.x = (a0.x + a1.x) + (a2.x + a3.x);
  acc.y = (a0.y + a1.y) + (a2.y + a3.y);
  acc.z = (a0.z + a1.z) + (a2.z + a3.z);
  acc.w = (a0.w + a1.w) + (a2.w + a3.w);
  float iv = inv[n];
  acc.x *= iv; acc.y *= iv; acc.z *= iv; acc.w *= iv;
  if (bias != nullptr) {
    const float4 b = *reinterpret_cast<const float4*>(&bias[q]);
    const float4 z = *reinterpret_cast<const float4*>(&Z[(size_t)n * 64 + q]);
    acc.x = fmaxf(acc.x + b.x + z.x, 0.0f);
    acc.y = fmaxf(acc.y + b.y + z.y, 0.0f);
    acc.z = fmaxf(acc.z + b.z + z.z, 0.0f);
    acc.w = fmaxf(acc.w + b.w + z.w, 0.0f);
  }
  *reinterpret_cast<float4*>(&out[(size_t)n * 64 + q]) = acc;
}

// ----------------------------------------------------------------- GEMM -----
// OUT[M x 64 cols] = act( A @ W + bias )
// dual==1: A = [S0 | S1] (each M x 64), W = [[WL],[WR]] stacked (wStride cols).
// dual==0: A = S0 (M x 128), W = WL (128 x wStride).
// grid.y: if colMulY, col block = 64*blockIdx.y of a wide W;
//         else blockIdx.y==1 switches to (WL2,WR2,OUT2) with colOff 0.
//
// sA layout: row-major [m][k2], stride 68.
//   writes: consecutive lanes -> consecutive k2 -> stride-1 banks (2-way, free)
//   reads:  float4 along k2 (16B-aligned: 68%4==0); per instr 4 distinct
//           addresses spaced 4*68 floats -> bank spacing 16 -> 2-way, free.
// (R3 transposed layout had lane-stride-68 writes = 8-way conflict, 2.4M
//  SQ_LDS_BANK_CONFLICT measured.)
__global__ __launch_bounds__(256) void k_gemm64(
    const float* __restrict__ S0, const float* __restrict__ S1, int dual,
    const float* __restrict__ WL, const float* __restrict__ WR, int wStride,
    int colMulY,
    const float* __restrict__ WL2, const float* __restrict__ WR2,
    float* __restrict__ OUT2,
    const float* __restrict__ bias, int doRelu,
    float* __restrict__ OUT, int outStride, int M) {
  __shared__ float sA[64 * 68];
  __shared__ float sW[128 * 64];
  __shared__ float sB[64];
  const int tid = threadIdx.x;

  int colOff = 0;
  if (colMulY) {
    colOff = 64 * blockIdx.y;
  } else if (blockIdx.y == 1) {
    WL = WL2; WR = WR2; OUT = OUT2;
  }

  for (int i = tid; i < 128 * 64; i += 256) {
    int k = i >> 6, c = i & 63;
    float w;
    if (dual)
      w = (k < 64) ? WL[k * wStride + colOff + c]
                   : WR[(k - 64) * wStride + colOff + c];
    else
      w = WL[k * wStride + colOff + c];
    sW[i] = w;
  }
  if (tid < 64) sB[tid] = bias ? bias[colOff + tid] : 0.0f;

  const int m0 = blockIdx.x * 64;
  const int tx = tid & 15, ty = tid >> 4;

  // stage A, K-half 0  (row-major, stride-1 lane writes)
  for (int i = tid; i < 64 * 64; i += 256) {
    int m = i >> 6, k2 = i & 63;
    int row = m0 + m;
    float v = 0.0f;
    if (row < M)
      v = dual ? S0[(size_t)row * 64 + k2] : S0[(size_t)row * 128 + k2];
    sA[m * 68 + k2] = v;
  }
  __syncthreads();

  float acc[4][4];
#pragma unroll
  for (int i = 0; i < 4; ++i)
#pragma unroll
    for (int j = 0; j < 4; ++j) acc[i][j] = sB[tx * 4 + j];

#pragma unroll 4
  for (int k4 = 0; k4 < 64; k4 += 4) {
    float4 aa[4], wb[4];
#pragma unroll
    for (int i = 0; i < 4; ++i)
      aa[i] = *reinterpret_cast<const float4*>(&sA[(ty * 4 + i) * 68 + k4]);
#pragma unroll
    for (int j = 0; j < 4; ++j)
      wb[j] = *reinterpret_cast<const float4*>(&sW[(k4 + j) * 64 + tx * 4]);
#pragma unroll
    for (int i = 0; i < 4; ++i) {
      acc[i][0] += aa[i].x * wb[0].x; acc[i][1] += aa[i].x * wb[0].y;
      acc[i][2] += aa[i].x * wb[0].z; acc[i][3] += aa[i].x * wb[0].w;
      acc[i][0] += aa[i].y * wb[1].x; acc[i][1] += aa[i].y * wb[1].y;
      acc[i][2] += aa[i].y * wb[1].z; acc[i][3] += aa[i].y * wb[1].w;
      acc[i][0] += aa[i].z * wb[2].x; acc[i][1] += aa[i].z * wb[2].y;
      acc[i][2] += aa[i].z * wb[2].z; acc[i][3] += aa[i].z * wb[2].w;
      acc[i][0] += aa[i].w * wb[3].x; acc[i][1] += aa[i].w * wb[3].y;
      acc[i][2] += aa[i].w * wb[3].z; acc[i][3] += aa[i].w * wb[3].w;
    }
  }
  __syncthreads();

  // stage A, K-half 1
  for (int i = tid; i < 64 * 64; i += 256) {
    int m = i >> 6, k2 = i & 63;
    int row = m0 + m;
    float v = 0.0f;
    if (row < M)
      v = dual ? S1[(size_t)row * 64 + k2] : S0[(size_t)row * 128 + 64 + k2];
    sA[m * 68 + k2] = v;
  }
  __syncthreads();

#pragma unroll 4
  for (int k4 = 0; k4 < 64; k4 += 4) {
    float4 aa[4], wb[4];
#pragma unroll
    for (int i = 0; i < 4; ++i)
      aa[i] = *reinterpret_cast<const float4*>(&sA[(ty * 4 + i) * 68 + k4]);
#pragma unroll
    for (int j = 0; j < 4; ++j)
      wb[j] = *reinterpret_cast<const float4*>(&sW[(64 + k4 + j) * 64 + tx * 4]);
#pragma unroll
    for (int i = 0; i < 4; ++i) {
      acc[i][0] += aa[i].x * wb[0].x; acc[i][1] += aa[i].x * wb[0].y;
      acc[i][2] += aa[i].x * wb[0].z; acc[i][3] += aa[i].x * wb[0].w;
      acc[i][0] += aa[i].y * wb[1].x; acc[i][1] += aa[i].y * wb[1].y;
      acc[i][2] += aa[i].y * wb[1].z; acc[i][3] += aa[i].y * wb[1].w;
      acc[i][0] += aa[i].z * wb[2].x; acc[i][1] += aa[i].z * wb[2].y;
      acc[i][2] += aa[i].z * wb[2].z; acc[i][3] += aa[i].z * wb[2].w;
      acc[i][0] += aa[i].w * wb[3].x; acc[i][1] += aa[i].w * wb[3].y;
      acc[i][2] += aa[i].w * wb[3].z; acc[i][3] += aa[i].w * wb[3].w;
    }
  }

#pragma unroll
  for (int i = 0; i < 4; ++i) {
    int row = m0 + ty * 4 + i;
    if (row < M) {
      float4 o = make_float4(acc[i][0], acc[i][1], acc[i][2], acc[i][3]);
      if (doRelu) {
        o.x = fmaxf(o.x, 0.0f); o.y = fmaxf(o.y, 0.0f);
        o.z = fmaxf(o.z, 0.0f); o.w = fmaxf(o.w, 0.0f);
      }
      *reinterpret_cast<float4*>(&OUT[(size_t)row * outStride + colOff + tx * 4]) = o;
    }
  }
}

// ----------------------------------------------- fused mean-pool + MLP ------
__global__ __launch_bounds__(64) void k_poolmlp(
    const float* __restrict__ H, const int* __restrict__ gstart,
    const float* __restrict__ w1, const float* __restrict__ b1,
    const float* __restrict__ w2, const float* __restrict__ b2,
    const float* __restrict__ w3, const float* __restrict__ b3,
    const float* __restrict__ w4, const float* __restrict__ b4,
    float* __restrict__ out) {
  __shared__ float sg[64], s1[64], s2[32], s3[32];
  int g = blockIdx.x, t = threadIdx.x;
  int beg = gstart[g], end = gstart[g + 1];
  float acc = 0.0f;
#pragma unroll 4
  for (int n = beg; n < end; ++n) acc += H[(size_t)n * 64 + t];
  float cnt = fmaxf((float)(end - beg), 1.0f);
  sg[t] = acc / cnt;
  __syncthreads();
  acc = b1[t];
  for (int k = 0; k < 64; ++k) acc += sg[k] * w1[k * 64 + t];
  s1[t] = fmaxf(acc, 0.0f);
  __syncthreads();
  if (t < 32) {
    acc = b2[t];
    for (int k = 0; k < 64; ++k) acc += s1[k] * w2[k * 32 + t];
    s2[t] = fmaxf(acc, 0.0f);
  }
  __syncthreads();
  if (t < 32) {
    acc = b3[t];
    for (int k = 0; k < 32; ++k) acc += s2[k] * w3[k * 32 + t];
    s3[t] = fmaxf(acc, 0.0f);
  }
  __syncthreads();
  if (t == 0) {
    acc = b4[0];
    for (int k = 0; k < 32; ++k) acc += s3[k] * w4[k];
    out[g] = acc;
  }
}

// ---------------------------------------------------------------- launch ----
extern "C" void kernel_launch(void* const* d_in, const int* in_sizes, int n_in,
                              void* d_out, int out_size, void* d_ws,
                              size_t ws_size, hipStream_t stream) {
  const float* x     = (const float*)d_in[0];
  const int*   ei    = (const int*)d_in[1];
  const int*   batch = (const int*)d_in[2];
  const int* src = ei;
  const int* dst = ei + NE;

  const float* c1_wl = (const float*)d_in[3];
  const float* c1_bl = (const float*)d_in[4];
  const float* c1_wr = (const float*)d_in[5];
  const float* c2_wl = (const float*)d_in[6];
  const float* c2_bl = (const float*)d_in[7];
  const float* c2_wr = (const float*)d_in[8];
  const float* c3_wl = (const float*)d_in[9];
  const float* c3_bl = (const float*)d_in[10];
  const float* c3_wr = (const float*)d_in[11];
  const float* c4_wl = (const float*)d_in[12];
  const float* c4_bl = (const float*)d_in[13];
  const float* c4_wr = (const float*)d_in[14];
  const float* l1w = (const float*)d_in[15];
  const float* l1b = (const float*)d_in[16];
  const float* l2w = (const float*)d_in[17];
  const float* l2b = (const float*)d_in[18];
  const float* l3w = (const float*)d_in[19];
  const float* l3b = (const float*)d_in[20];
  const float* l4w = (const float*)d_in[21];
  const float* l4b = (const float*)d_in[22];

  // ---- workspace carve-up
  float* ws = (float*)d_ws;
  float* inv = ws;                        // NN
  float* B1  = inv + NN;                  // NN*64   (agg / h2 / h4)
  float* B2  = B1 + (size_t)NN * 64;      // NN*128  (h1)
  float* B3  = B2 + (size_t)NN * 128;     // NN*64   (U / agg scratch)
  float* B4  = B3 + (size_t)NN * 64;      // NN*64   (V / h3)
  int* cnt    = (int*)(B4 + (size_t)NN * 64);  // NN
  int* off    = cnt + NN;                 // NN+1
  int* cursor = off + NN + 1;             // NN
  int* bsum   = cursor + NN;              // 512
  int* gstart = bsum + 512;               // NG+1
  int* csr    = gstart + NG + 1 + 3;      // NE

  const int gE   = (NE + 255) / 256;  // 6250
  const int gN16 = NN * 16 / 256;     // 6250  (gather)
  const int gM   = (NN + 63) / 64;    // 1563  (gemm x)
  const int gN   = NBLK_SCAN;         // 391

  hipMemsetAsync(cnt, 0, (size_t)NN * 4, stream);

  // ---- CSR build (reused by all 4 layers) + graph bounds
  k_count<<<gE, 256, 0, stream>>>(dst, cnt);
  k_scan1<<<gN, 256, 0, stream>>>(cnt, off, bsum);
  k_scan2<<<1, 512, 0, stream>>>(bsum);
  k_scan3<<<gN, 256, 0, stream>>>(off, bsum, cursor, cnt, inv);
  k_fill<<<gE, 256, 0, stream>>>(src, dst, cursor, csr);
  k_bounds<<<5, 256, 0, stream>>>(batch, gstart);

  // ---- layer 1: B2(h1) = relu([agg(x) | x] @ [[c1_wl],[c1_wr]] + c1_bl)
  k_gather<<<gN16, 256, 0, stream>>>(x, csr, off, inv, nullptr, nullptr, B1);
  k_gemm64<<<dim3(gM, 2), 256, 0, stream>>>(B1, x, 1, c1_wl, c1_wr, 128, 1,
                                            nullptr, nullptr, nullptr,
                                            c1_bl, 1, B2, 128, NN);

  // ---- layer 2: B3 = h1@wl, B4 = h1@wr; B1(h2) = relu(agg(B3) + b + B4)
  k_gemm64<<<dim3(gM, 2), 256, 0, stream>>>(B2, nullptr, 0, c2_wl, nullptr, 64, 0,
                                            c2_wr, nullptr, B4,
                                            nullptr, 0, B3, 64, NN);
  k_gather<<<gN16, 256, 0, stream>>>(B3, csr, off, inv, c2_bl, B4, B1);

  // ---- layer 3: B4(h3) = relu([agg(h2) | h2] @ [[c3_wl],[c3_wr]] + c3_bl)
  k_gather<<<gN16, 256, 0, stream>>>(B1, csr, off, inv, nullptr, nullptr, B3);
  k_gemm64<<<dim3(gM, 1), 256, 0, stream>>>(B3, B1, 1, c3_wl, c3_wr, 64, 0,
                                            nullptr, nullptr, nullptr,
                                            c3_bl, 1, B4, 64, NN);

  // ---- layer 4: B1(h4) = relu([agg(h3) | h3] @ [[c4_wl],[c4_wr]] + c4_bl)
  k_gather<<<gN16, 256, 0, stream>>>(B4, csr, off, inv, nullptr, nullptr, B3);
  k_gemm64<<<dim3(gM, 1), 256, 0, stream>>>(B3, B4, 1, c4_wl, c4_wr, 64, 0,
                                            nullptr, nullptr, nullptr,
                                            c4_bl, 1, B1, 64, NN);

  // ---- fused pool + MLP (batch sorted -> contiguous segments, no atomics)
  k_poolmlp<<<NG, 64, 0, stream>>>(B1, gstart, l1w, l1b, l2w, l2b,
                                   l3w, l3b, l4w, l4b, (float*)d_out);
}

// Round 5
// 698.862 us; speedup vs baseline: 1.3254x; 1.3254x over previous
//
#include <hip/hip_runtime.h>

#define NN 100000
#define NE 1600000
#define NG 1024
#define NBLK_SCAN ((NN + 255) / 256)  // 391
#define NPART 8                        // k_fill dst partitions; NN%8==0

// ------------------------------------------------------------- CSR build ----
// count + per-edge rank (removes the atomic pass from k_fill)
__global__ __launch_bounds__(256) void k_count(const int* __restrict__ dst,
                                               int* __restrict__ cnt,
                                               int* __restrict__ rank) {
  int e = blockIdx.x * 256 + threadIdx.x;
  if (e < NE) rank[e] = atomicAdd(&cnt[dst[e]], 1);
}

__global__ __launch_bounds__(256) void k_scan1(const int* __restrict__ cnt,
                                               int* __restrict__ off,
                                               int* __restrict__ bsum) {
  __shared__ int s[256];
  int tid = threadIdx.x;
  int i = blockIdx.x * 256 + tid;
  int v = (i < NN) ? cnt[i] : 0;
  s[tid] = v;
  __syncthreads();
  for (int d = 1; d < 256; d <<= 1) {
    int t = (tid >= d) ? s[tid - d] : 0;
    __syncthreads();
    s[tid] += t;
    __syncthreads();
  }
  if (i < NN) off[i] = s[tid] - v;  // exclusive
  if (tid == 255) bsum[blockIdx.x] = s[255];
}

__global__ __launch_bounds__(512) void k_scan2(int* __restrict__ bsum) {
  __shared__ int s[512];
  int tid = threadIdx.x;
  int v = (tid < NBLK_SCAN) ? bsum[tid] : 0;
  s[tid] = v;
  __syncthreads();
  for (int d = 1; d < 512; d <<= 1) {
    int t = (tid >= d) ? s[tid - d] : 0;
    __syncthreads();
    s[tid] += t;
    __syncthreads();
  }
  if (tid < NBLK_SCAN) bsum[tid] = s[tid] - v;  // exclusive
}

// scan stage 3 + invdeg fused
__global__ __launch_bounds__(256) void k_scan3(int* __restrict__ off,
                                               const int* __restrict__ bsum,
                                               const int* __restrict__ cnt,
                                               float* __restrict__ inv) {
  int i = blockIdx.x * 256 + threadIdx.x;
  if (i < NN) {
    off[i] = off[i] + bsum[blockIdx.x];
    inv[i] = 1.0f / fmaxf((float)cnt[i], 1.0f);
  }
  if (i == 0) off[NN] = NE;
}

// partitioned fill: blockIdx.y owns dst range [y*NN/8,(y+1)*NN/8).
// x-fastest dispatch => concurrent blocks share one ~0.8MB csr window
// (fits per-XCD L2) instead of thrashing the whole 6.4MB randomly.
__global__ __launch_bounds__(256) void k_fill(const int* __restrict__ src,
                                              const int* __restrict__ dst,
                                              const int* __restrict__ off,
                                              const int* __restrict__ rank,
                                              int* __restrict__ csr) {
  int e = blockIdx.x * 256 + threadIdx.x;
  int lo = (int)blockIdx.y * (NN / NPART);
  int hi = lo + (NN / NPART);
  if (e < NE) {
    int d = dst[e];
    if (d >= lo && d < hi) csr[off[d] + rank[e]] = src[e];
  }
}

// graph segment boundaries in the SORTED batch array
__global__ __launch_bounds__(256) void k_bounds(const int* __restrict__ batch,
                                                int* __restrict__ gstart) {
  int g = blockIdx.x * 256 + threadIdx.x;
  if (g > NG) return;
  int lo = 0, hi = NN;
  while (lo < hi) {
    int mid = (lo + hi) >> 1;
    if (batch[mid] < g) lo = mid + 1; else hi = mid;
  }
  gstart[g] = lo;
}

// --------------------------------------------------------- gather-aggregate -
__global__ __launch_bounds__(256) void k_gather(const float* __restrict__ F,
                                                const int* __restrict__ csr,
                                                const int* __restrict__ off,
                                                const float* __restrict__ inv,
                                                const float* __restrict__ bias,
                                                const float* __restrict__ Z,
                                                float* __restrict__ out) {
  int idx = blockIdx.x * 256 + threadIdx.x;  // grid = NN*16 threads
  int n = idx >> 4;
  int q = (idx & 15) << 2;
  int beg = off[n], end = off[n + 1];
  float4 a0 = make_float4(0.f, 0.f, 0.f, 0.f);
  float4 a1 = a0, a2 = a0, a3 = a0;
  int e = beg;
  for (; e + 4 <= end; e += 4) {
    int s0 = csr[e], s1 = csr[e + 1], s2 = csr[e + 2], s3 = csr[e + 3];
    const float4 v0 = *reinterpret_cast<const float4*>(&F[(size_t)s0 * 64 + q]);
    const float4 v1 = *reinterpret_cast<const float4*>(&F[(size_t)s1 * 64 + q]);
    const float4 v2 = *reinterpret_cast<const float4*>(&F[(size_t)s2 * 64 + q]);
    const float4 v3 = *reinterpret_cast<const float4*>(&F[(size_t)s3 * 64 + q]);
    a0.x += v0.x; a0.y += v0.y; a0.z += v0.z; a0.w += v0.w;
    a1.x += v1.x; a1.y += v1.y; a1.z += v1.z; a1.w += v1.w;
    a2.x += v2.x; a2.y += v2.y; a2.z += v2.z; a2.w += v2.w;
    a3.x += v3.x; a3.y += v3.y; a3.z += v3.z; a3.w += v3.w;
  }
  for (; e < end; ++e) {
    int s0 = csr[e];
    const float4 v0 = *reinterpret_cast<const float4*>(&F[(size_t)s0 * 64 + q]);
    a0.x += v0.x; a0.y += v0.y; a0.z += v0.z; a0.w += v0.w;
  }
  float4 acc;
  acc.x = (a0.x + a1.x) + (a2.x + a3.x);
  acc.y = (a0.y + a1.y) + (a2.y + a3.y);
  acc.z = (a0.z + a1.z) + (a2.z + a3.z);
  acc.w = (a0.w + a1.w) + (a2.w + a3.w);
  float iv = inv[n];
  acc.x *= iv; acc.y *= iv; acc.z *= iv; acc.w *= iv;
  if (bias != nullptr) {
    const float4 b = *reinterpret_cast<const float4*>(&bias[q]);
    const float4 z = *reinterpret_cast<const float4*>(&Z[(size_t)n * 64 + q]);
    acc.x = fmaxf(acc.x + b.x + z.x, 0.0f);
    acc.y = fmaxf(acc.y + b.y + z.y, 0.0f);
    acc.z = fmaxf(acc.z + b.z + z.z, 0.0f);
    acc.w = fmaxf(acc.w + b.w + z.w, 0.0f);
  }
  *reinterpret_cast<float4*>(&out[(size_t)n * 64 + q]) = acc;
}

// ----------------------------------------------------------------- GEMM -----
// OUT[M x 64 cols] = act( A @ W + bias ), K = 128.
// dual==1: A = [S0 | S1] (each M x 64), W = [[WL],[WR]] stacked (wStride cols).
// dual==0: A = S0 (M x 128), W = WL (128 x wStride).
// grid.y: if colMulY, col block = 64*blockIdx.y; else y==1 -> (WL2,WR2,OUT2).
//
// R5 design (R4 was latency-bound: VALUBusy 31%, Occ 20%, LDS 49.5KB):
//  - no sW: W rows read as float4 from global per k (W <= 64KB, L1/L2-hot,
//    uniform-per-block addresses across ty -> 16 distinct addrs/wave)
//  - sA holds all 128 K (64x132 fp32 = 33.8KB LDS total -> 4 blocks/CU)
//  - staging = 8 float4 loads/thread, ONE __syncthreads (was 48 scalar + 3)
#define FMA_BLK()                                                              \
  _Pragma("unroll") for (int i = 0; i < 4; ++i) {                              \
    acc[i][0] += aa[i].x * wb[0].x; acc[i][1] += aa[i].x * wb[0].y;            \
    acc[i][2] += aa[i].x * wb[0].z; acc[i][3] += aa[i].x * wb[0].w;            \
    acc[i][0] += aa[i].y * wb[1].x; acc[i][1] += aa[i].y * wb[1].y;            \
    acc[i][2] += aa[i].y * wb[1].z; acc[i][3] += aa[i].y * wb[1].w;            \
    acc[i][0] += aa[i].z * wb[2].x; acc[i][1] += aa[i].z * wb[2].y;            \
    acc[i][2] += aa[i].z * wb[2].z; acc[i][3] += aa[i].z * wb[2].w;            \
    acc[i][0] += aa[i].w * wb[3].x; acc[i][1] += aa[i].w * wb[3].y;            \
    acc[i][2] += aa[i].w * wb[3].z; acc[i][3] += aa[i].w * wb[3].w;            \
  }

__global__ __launch_bounds__(256) void k_gemm64(
    const float* __restrict__ S0, const float* __restrict__ S1, int dual,
    const float* __restrict__ WL, const float* __restrict__ WR, int wStride,
    int colMulY,
    const float* __restrict__ WL2, const float* __restrict__ WR2,
    float* __restrict__ OUT2,
    const float* __restrict__ bias, int doRelu,
    float* __restrict__ OUT, int outStride, int M) {
  __shared__ float sA[64 * 132];
  const int tid = threadIdx.x;

  int colOff = 0;
  if (colMulY) {
    colOff = 64 * blockIdx.y;
  } else if (blockIdx.y == 1) {
    WL = WL2; WR = WR2; OUT = OUT2;
  }

  const int m0 = blockIdx.x * 64;
  const int tx = tid & 15, ty = tid >> 4;

  // ---- stage A (all 128 K), vectorized: 8 float4 per thread
#pragma unroll
  for (int l = 0; l < 8; ++l) {
    int lin = (tid + l * 256) << 2;  // flat float index in 64x128 tile
    int m = lin >> 7;
    int k = lin & 127;
    int row = m0 + m;
    float4 v = make_float4(0.f, 0.f, 0.f, 0.f);
    if (row < M) {
      if (dual)
        v = (k < 64)
                ? *reinterpret_cast<const float4*>(&S0[(size_t)row * 64 + k])
                : *reinterpret_cast<const float4*>(&S1[(size_t)row * 64 + (k - 64)]);
      else
        v = *reinterpret_cast<const float4*>(&S0[(size_t)row * 128 + k]);
    }
    *reinterpret_cast<float4*>(&sA[m * 132 + k]) = v;
  }

  // ---- acc init from bias (global, L2-hot)
  float4 bv = make_float4(0.f, 0.f, 0.f, 0.f);
  if (bias) bv = *reinterpret_cast<const float4*>(&bias[colOff + tx * 4]);
  float acc[4][4];
#pragma unroll
  for (int i = 0; i < 4; ++i) {
    acc[i][0] = bv.x; acc[i][1] = bv.y; acc[i][2] = bv.z; acc[i][3] = bv.w;
  }

  const float* pW0 = WL + colOff + tx * 4;                       // k in [0,64)
  const float* pW1 = dual ? (WR + colOff + tx * 4)
                          : (WL + (size_t)64 * wStride + colOff + tx * 4);

  __syncthreads();

  // ---- K-half 0
#pragma unroll 4
  for (int k4 = 0; k4 < 64; k4 += 4) {
    float4 wb[4], aa[4];
#pragma unroll
    for (int j = 0; j < 4; ++j)
      wb[j] = *reinterpret_cast<const float4*>(pW0 + (size_t)(k4 + j) * wStride);
#pragma unroll
    for (int i = 0; i < 4; ++i)
      aa[i] = *reinterpret_cast<const float4*>(&sA[(ty * 4 + i) * 132 + k4]);
    FMA_BLK()
  }
  // ---- K-half 1
#pragma unroll 4
  for (int k4 = 0; k4 < 64; k4 += 4) {
    float4 wb[4], aa[4];
#pragma unroll
    for (int j = 0; j < 4; ++j)
      wb[j] = *reinterpret_cast<const float4*>(pW1 + (size_t)(k4 + j) * wStride);
#pragma unroll
    for (int i = 0; i < 4; ++i)
      aa[i] = *reinterpret_cast<const float4*>(&sA[(ty * 4 + i) * 132 + 64 + k4]);
    FMA_BLK()
  }

#pragma unroll
  for (int i = 0; i < 4; ++i) {
    int row = m0 + ty * 4 + i;
    if (row < M) {
      float4 o = make_float4(acc[i][0], acc[i][1], acc[i][2], acc[i][3]);
      if (doRelu) {
        o.x = fmaxf(o.x, 0.0f); o.y = fmaxf(o.y, 0.0f);
        o.z = fmaxf(o.z, 0.0f); o.w = fmaxf(o.w, 0.0f);
      }
      *reinterpret_cast<float4*>(&OUT[(size_t)row * outStride + colOff + tx * 4]) = o;
    }
  }
}

// ----------------------------------------------- fused mean-pool + MLP ------
__global__ __launch_bounds__(64) void k_poolmlp(
    const float* __restrict__ H, const int* __restrict__ gstart,
    const float* __restrict__ w1, const float* __restrict__ b1,
    const float* __restrict__ w2, const float* __restrict__ b2,
    const float* __restrict__ w3, const float* __restrict__ b3,
    const float* __restrict__ w4, const float* __restrict__ b4,
    float* __restrict__ out) {
  __shared__ float sg[64], s1[64], s2[32], s3[32];
  int g = blockIdx.x, t = threadIdx.x;
  int beg = gstart[g], end = gstart[g + 1];
  float acc = 0.0f;
#pragma unroll 4
  for (int n = beg; n < end; ++n) acc += H[(size_t)n * 64 + t];
  float cnt = fmaxf((float)(end - beg), 1.0f);
  sg[t] = acc / cnt;
  __syncthreads();
  acc = b1[t];
  for (int k = 0; k < 64; ++k) acc += sg[k] * w1[k * 64 + t];
  s1[t] = fmaxf(acc, 0.0f);
  __syncthreads();
  if (t < 32) {
    acc = b2[t];
    for (int k = 0; k < 64; ++k) acc += s1[k] * w2[k * 32 + t];
    s2[t] = fmaxf(acc, 0.0f);
  }
  __syncthreads();
  if (t < 32) {
    acc = b3[t];
    for (int k = 0; k < 32; ++k) acc += s2[k] * w3[k * 32 + t];
    s3[t] = fmaxf(acc, 0.0f);
  }
  __syncthreads();
  if (t == 0) {
    acc = b4[0];
    for (int k = 0; k < 32; ++k) acc += s3[k] * w4[k];
    out[g] = acc;
  }
}

// ---------------------------------------------------------------- launch ----
extern "C" void kernel_launch(void* const* d_in, const int* in_sizes, int n_in,
                              void* d_out, int out_size, void* d_ws,
                              size_t ws_size, hipStream_t stream) {
  const float* x     = (const float*)d_in[0];
  const int*   ei    = (const int*)d_in[1];
  const int*   batch = (const int*)d_in[2];
  const int* src = ei;
  const int* dst = ei + NE;

  const float* c1_wl = (const float*)d_in[3];
  const float* c1_bl = (const float*)d_in[4];
  const float* c1_wr = (const float*)d_in[5];
  const float* c2_wl = (const float*)d_in[6];
  const float* c2_bl = (const float*)d_in[7];
  const float* c2_wr = (const float*)d_in[8];
  const float* c3_wl = (const float*)d_in[9];
  const float* c3_bl = (const float*)d_in[10];
  const float* c3_wr = (const float*)d_in[11];
  const float* c4_wl = (const float*)d_in[12];
  const float* c4_bl = (const float*)d_in[13];
  const float* c4_wr = (const float*)d_in[14];
  const float* l1w = (const float*)d_in[15];
  const float* l1b = (const float*)d_in[16];
  const float* l2w = (const float*)d_in[17];
  const float* l2b = (const float*)d_in[18];
  const float* l3w = (const float*)d_in[19];
  const float* l3b = (const float*)d_in[20];
  const float* l4w = (const float*)d_in[21];
  const float* l4b = (const float*)d_in[22];

  // ---- workspace carve-up
  float* ws = (float*)d_ws;
  float* inv = ws;                        // NN
  float* B1  = inv + NN;                  // NN*64   (agg / h2 / h4)
  float* B2  = B1 + (size_t)NN * 64;      // NN*128  (h1)
  float* B3  = B2 + (size_t)NN * 128;     // NN*64
  float* B4  = B3 + (size_t)NN * 64;      // NN*64
  int* cnt    = (int*)(B4 + (size_t)NN * 64);  // NN
  int* off    = cnt + NN;                 // NN+1
  int* bsum   = off + NN + 1;             // 512
  int* gstart = bsum + 512;               // NG+1
  int* csr    = gstart + NG + 1 + 2;      // NE
  int* rank   = csr + NE;                 // NE

  const int gE   = (NE + 255) / 256;  // 6250
  const int gN16 = NN * 16 / 256;     // 6250  (gather)
  const int gM   = (NN + 63) / 64;    // 1563  (gemm x)
  const int gN   = NBLK_SCAN;         // 391

  hipMemsetAsync(cnt, 0, (size_t)NN * 4, stream);

  // ---- CSR build (reused by all 4 layers) + graph bounds
  k_count<<<gE, 256, 0, stream>>>(dst, cnt, rank);
  k_scan1<<<gN, 256, 0, stream>>>(cnt, off, bsum);
  k_scan2<<<1, 512, 0, stream>>>(bsum);
  k_scan3<<<gN, 256, 0, stream>>>(off, bsum, cnt, inv);
  k_fill<<<dim3(gE, NPART), 256, 0, stream>>>(src, dst, off, rank, csr);
  k_bounds<<<5, 256, 0, stream>>>(batch, gstart);

  // ---- layer 1: B2(h1) = relu([agg(x) | x] @ [[c1_wl],[c1_wr]] + c1_bl)
  k_gather<<<gN16, 256, 0, stream>>>(x, csr, off, inv, nullptr, nullptr, B1);
  k_gemm64<<<dim3(gM, 2), 256, 0, stream>>>(B1, x, 1, c1_wl, c1_wr, 128, 1,
                                            nullptr, nullptr, nullptr,
                                            c1_bl, 1, B2, 128, NN);

  // ---- layer 2: B3 = h1@wl, B4 = h1@wr; B1(h2) = relu(agg(B3) + b + B4)
  k_gemm64<<<dim3(gM, 2), 256, 0, stream>>>(B2, nullptr, 0, c2_wl, nullptr, 64, 0,
                                            c2_wr, nullptr, B4,
                                            nullptr, 0, B3, 64, NN);
  k_gather<<<gN16, 256, 0, stream>>>(B3, csr, off, inv, c2_bl, B4, B1);

  // ---- layer 3: B4(h3) = relu([agg(h2) | h2] @ [[c3_wl],[c3_wr]] + c3_bl)
  k_gather<<<gN16, 256, 0, stream>>>(B1, csr, off, inv, nullptr, nullptr, B3);
  k_gemm64<<<dim3(gM, 1), 256, 0, stream>>>(B3, B1, 1, c3_wl, c3_wr, 64, 0,
                                            nullptr, nullptr, nullptr,
                                            c3_bl, 1, B4, 64, NN);

  // ---- layer 4: B1(h4) = relu([agg(h3) | h3] @ [[c4_wl],[c4_wr]] + c4_bl)
  k_gather<<<gN16, 256, 0, stream>>>(B4, csr, off, inv, nullptr, nullptr, B3);
  k_gemm64<<<dim3(gM, 1), 256, 0, stream>>>(B3, B4, 1, c4_wl, c4_wr, 64, 0,
                                            nullptr, nullptr, nullptr,
                                            c4_bl, 1, B1, 64, NN);

  // ---- fused pool + MLP (batch sorted -> contiguous segments, no atomics)
  k_poolmlp<<<NG, 64, 0, stream>>>(B1, gstart, l1w, l1b, l2w, l2b,
                                   l3w, l3b, l4w, l4b, (float*)d_out);
}

// Round 6
// 437.952 us; speedup vs baseline: 2.1150x; 1.5958x over previous
//
#include <hip/hip_runtime.h>

#define NN 100000
#define NE 1600000
#define NG 1024
#define NBLK_SCAN ((NN + 255) / 256)  // 391
#define NPART 8

typedef __attribute__((ext_vector_type(8))) short bf16x8;
typedef __attribute__((ext_vector_type(4))) float f32x4;

__device__ __forceinline__ unsigned f2bf1(float f) {
  union { float f; unsigned u; } v; v.f = f;
  return (v.u + 0x7fffu + ((v.u >> 16) & 1u)) >> 16;  // RNE
}
__device__ __forceinline__ unsigned packbf2(float a, float b) {
  return f2bf1(a) | (f2bf1(b) << 16);
}
__device__ __forceinline__ float bflo(unsigned u) {
  union { unsigned u; float f; } v; v.u = u << 16; return v.f;
}
__device__ __forceinline__ float bfhi(unsigned u) {
  union { unsigned u; float f; } v; v.u = u & 0xffff0000u; return v.f;
}
__device__ __forceinline__ float bfs(unsigned short s) {
  union { unsigned u; float f; } v; v.u = ((unsigned)s) << 16; return v.f;
}

// ------------------------------------------------------------- CSR build ----
__global__ __launch_bounds__(256) void k_count(const int* __restrict__ dst,
                                               int* __restrict__ cnt,
                                               int* __restrict__ rank) {
  int e = blockIdx.x * 256 + threadIdx.x;
  if (e < NE) rank[e] = atomicAdd(&cnt[dst[e]], 1);
}

__global__ __launch_bounds__(256) void k_scan1(const int* __restrict__ cnt,
                                               int* __restrict__ off,
                                               int* __restrict__ bsum) {
  __shared__ int s[256];
  int tid = threadIdx.x;
  int i = blockIdx.x * 256 + tid;
  int v = (i < NN) ? cnt[i] : 0;
  s[tid] = v;
  __syncthreads();
  for (int d = 1; d < 256; d <<= 1) {
    int t = (tid >= d) ? s[tid - d] : 0;
    __syncthreads();
    s[tid] += t;
    __syncthreads();
  }
  if (i < NN) off[i] = s[tid] - v;
  if (tid == 255) bsum[blockIdx.x] = s[255];
}

__global__ __launch_bounds__(512) void k_scan2(int* __restrict__ bsum) {
  __shared__ int s[512];
  int tid = threadIdx.x;
  int v = (tid < NBLK_SCAN) ? bsum[tid] : 0;
  s[tid] = v;
  __syncthreads();
  for (int d = 1; d < 512; d <<= 1) {
    int t = (tid >= d) ? s[tid - d] : 0;
    __syncthreads();
    s[tid] += t;
    __syncthreads();
  }
  if (tid < NBLK_SCAN) bsum[tid] = s[tid] - v;
}

__global__ __launch_bounds__(256) void k_scan3(int* __restrict__ off,
                                               const int* __restrict__ bsum,
                                               const int* __restrict__ cnt,
                                               float* __restrict__ inv) {
  int i = blockIdx.x * 256 + threadIdx.x;
  if (i < NN) {
    off[i] = off[i] + bsum[blockIdx.x];
    inv[i] = 1.0f / fmaxf((float)cnt[i], 1.0f);
  }
  if (i == 0) off[NN] = NE;
}

__global__ __launch_bounds__(256) void k_fill(const int* __restrict__ src,
                                              const int* __restrict__ dst,
                                              const int* __restrict__ off,
                                              const int* __restrict__ rank,
                                              int* __restrict__ csr) {
  int e = blockIdx.x * 256 + threadIdx.x;
  int lo = (int)blockIdx.y * (NN / NPART);
  int hi = lo + (NN / NPART);
  if (e < NE) {
    int d = dst[e];
    if (d >= lo && d < hi) csr[off[d] + rank[e]] = src[e];
  }
}

__global__ __launch_bounds__(256) void k_bounds(const int* __restrict__ batch,
                                                int* __restrict__ gstart) {
  int g = blockIdx.x * 256 + threadIdx.x;
  if (g > NG) return;
  int lo = 0, hi = NN;
  while (lo < hi) {
    int mid = (lo + hi) >> 1;
    if (batch[mid] < g) lo = mid + 1; else hi = mid;
  }
  gstart[g] = lo;
}

// ------------------------------------------------------- fp32 -> bf16 x -----
__global__ __launch_bounds__(256) void k_cvt(const float* __restrict__ X,
                                             unsigned short* __restrict__ Xb) {
  int i = blockIdx.x * 256 + threadIdx.x;  // 800000 threads, 8 floats each
  const float4* p = (const float4*)X + (size_t)i * 2;
  float4 a = p[0], b = p[1];
  uint4 o;
  o.x = packbf2(a.x, a.y); o.y = packbf2(a.z, a.w);
  o.z = packbf2(b.x, b.y); o.w = packbf2(b.z, b.w);
  ((uint4*)Xb)[i] = o;
}

// --------------------------------------- pack conv weights to B-frag bf16 ---
// frag for (k,n), K=128: t=k>>5, kq=(k>>3)&3, j=k&7, n0=n>>4, nl=n&15,
// lane=kq*16+nl; dst[((n0*4+t)*64+lane)*8 + j]
__global__ __launch_bounds__(256) void k_prep(
    const float* __restrict__ c1wl, const float* __restrict__ c1wr,
    const float* __restrict__ c2wl, const float* __restrict__ c2wr,
    const float* __restrict__ c3wl, const float* __restrict__ c3wr,
    const float* __restrict__ c4wl, const float* __restrict__ c4wr,
    unsigned short* __restrict__ pL1, unsigned short* __restrict__ pL2a,
    unsigned short* __restrict__ pL2b, unsigned short* __restrict__ pL3,
    unsigned short* __restrict__ pL4) {
  int yb = blockIdx.y;
  const float *WL, *WR; unsigned short* dst; int N;
  if (yb == 0)      { WL = c1wl; WR = c1wr;         dst = pL1;  N = 128; }
  else if (yb == 1) { WL = c2wl; WR = c2wl + 64*64; dst = pL2a; N = 64; }
  else if (yb == 2) { WL = c2wr; WR = c2wr + 64*64; dst = pL2b; N = 64; }
  else if (yb == 3) { WL = c3wl; WR = c3wr;         dst = pL3;  N = 64; }
  else              { WL = c4wl; WR = c4wr;         dst = pL4;  N = 64; }
  int e = blockIdx.x * 256 + threadIdx.x;
  if (e >= 128 * N) return;
  int k = e / N, n = e - k * N;                    // ld == N in all cases
  float w = (k < 64) ? WL[k * N + n] : WR[(k - 64) * N + n];
  int t = k >> 5, kq = (k >> 3) & 3, j = k & 7;
  int n0 = n >> 4, nl = n & 15;
  dst[((((n0 * 4 + t) * 64) + (kq * 16 + nl)) << 3) + j] = (unsigned short)f2bf1(w);
}

// --------------------------------------------------- gather (bf16 features) -
// 8 thr/node, 8 channels each (16B). fp32 accumulate, bf16 out.
__global__ __launch_bounds__(256) void k_gather(
    const unsigned short* __restrict__ F, const int* __restrict__ csr,
    const int* __restrict__ off, const float* __restrict__ inv,
    const float* __restrict__ bias, const unsigned short* __restrict__ Z,
    unsigned short* __restrict__ out) {
  int idx = blockIdx.x * 256 + threadIdx.x;  // grid = NN*8 threads
  int n = idx >> 3, q = idx & 7;
  int beg = off[n], end = off[n + 1];
  float a[8];
#pragma unroll
  for (int c = 0; c < 8; ++c) a[c] = 0.f;
  int e = beg;
  for (; e + 4 <= end; e += 4) {
    int s0 = csr[e], s1 = csr[e + 1], s2 = csr[e + 2], s3 = csr[e + 3];
    uint4 v0 = ((const uint4*)(F + (size_t)s0 * 64))[q];
    uint4 v1 = ((const uint4*)(F + (size_t)s1 * 64))[q];
    uint4 v2 = ((const uint4*)(F + (size_t)s2 * 64))[q];
    uint4 v3 = ((const uint4*)(F + (size_t)s3 * 64))[q];
    a[0] += (bflo(v0.x) + bflo(v1.x)) + (bflo(v2.x) + bflo(v3.x));
    a[1] += (bfhi(v0.x) + bfhi(v1.x)) + (bfhi(v2.x) + bfhi(v3.x));
    a[2] += (bflo(v0.y) + bflo(v1.y)) + (bflo(v2.y) + bflo(v3.y));
    a[3] += (bfhi(v0.y) + bfhi(v1.y)) + (bfhi(v2.y) + bfhi(v3.y));
    a[4] += (bflo(v0.z) + bflo(v1.z)) + (bflo(v2.z) + bflo(v3.z));
    a[5] += (bfhi(v0.z) + bfhi(v1.z)) + (bfhi(v2.z) + bfhi(v3.z));
    a[6] += (bflo(v0.w) + bflo(v1.w)) + (bflo(v2.w) + bflo(v3.w));
    a[7] += (bfhi(v0.w) + bfhi(v1.w)) + (bfhi(v2.w) + bfhi(v3.w));
  }
  for (; e < end; ++e) {
    uint4 v0 = ((const uint4*)(F + (size_t)csr[e] * 64))[q];
    a[0] += bflo(v0.x); a[1] += bfhi(v0.x);
    a[2] += bflo(v0.y); a[3] += bfhi(v0.y);
    a[4] += bflo(v0.z); a[5] += bfhi(v0.z);
    a[6] += bflo(v0.w); a[7] += bfhi(v0.w);
  }
  float iv = inv[n];
#pragma unroll
  for (int c = 0; c < 8; ++c) a[c] *= iv;
  if (bias != nullptr) {  // layer-2 epilogue: relu(agg + bias + Z)
    uint4 z = ((const uint4*)(Z + (size_t)n * 64))[q];
    const float4* bp = (const float4*)(bias + q * 8);
    float4 b0 = bp[0], b1 = bp[1];
    a[0] = fmaxf(a[0] + b0.x + bflo(z.x), 0.f);
    a[1] = fmaxf(a[1] + b0.y + bfhi(z.x), 0.f);
    a[2] = fmaxf(a[2] + b0.z + bflo(z.y), 0.f);
    a[3] = fmaxf(a[3] + b0.w + bfhi(z.y), 0.f);
    a[4] = fmaxf(a[4] + b1.x + bflo(z.z), 0.f);
    a[5] = fmaxf(a[5] + b1.y + bfhi(z.z), 0.f);
    a[6] = fmaxf(a[6] + b1.z + bflo(z.w), 0.f);
    a[7] = fmaxf(a[7] + b1.w + bfhi(z.w), 0.f);
  }
  uint4 o;
  o.x = packbf2(a[0], a[1]); o.y = packbf2(a[2], a[3]);
  o.z = packbf2(a[4], a[5]); o.w = packbf2(a[6], a[7]);
  ((uint4*)(out + (size_t)n * 64))[q] = o;
}

// ------------------------------------------------------------ MFMA GEMM -----
// OUT[M x 64 cols @ colOff] = act( [S0|S1] @ W + bias ), K=128, bf16 in/out.
// A staged in LDS pre-swizzled to MFMA A-frag order: wave reads contiguous
// 1KB per ds_read_b128 sweep (conflict-free). W pre-packed B-frags (global,
// L1-hot, 8-16KB). C transposed through LDS (reusing A space) for coalesced
// bf16x8 stores. LDS 16.9KB -> ~8 blocks/CU.
__global__ __launch_bounds__(256) void k_gemm(
    const unsigned short* __restrict__ S0, const unsigned short* __restrict__ S1,
    int dual,
    const unsigned short* __restrict__ Wp, int colMulY,
    const unsigned short* __restrict__ Wp2, unsigned short* __restrict__ OUT2,
    const float* __restrict__ bias, int doRelu,
    unsigned short* __restrict__ OUT, int outStride, int M) {
  __shared__ __align__(16) char smem[64 * 66 * 4];  // sA 16384B / sC 16896B
  unsigned short* sA = (unsigned short*)smem;
  float* sC = (float*)smem;
  const int tid = threadIdx.x;

  int colOff = 0;
  if (colMulY) colOff = 64 * blockIdx.y;
  else if (blockIdx.y == 1) { Wp = Wp2; OUT = OUT2; }

  const int m0 = blockIdx.x * 64;

  // ---- stage A (64 rows x 128 k) into A-frag order
#pragma unroll
  for (int l = 0; l < 4; ++l) {
    int c = tid + l * 256;     // 1024 chunks of bf16x8
    int m = c >> 4, k8 = c & 15;
    int row = m0 + m;
    uint4 v = make_uint4(0, 0, 0, 0);
    if (row < M) {
      if (dual)
        v = (k8 < 8) ? ((const uint4*)(S0 + (size_t)row * 64))[k8]
                     : ((const uint4*)(S1 + (size_t)row * 64))[k8 - 8];
      else
        v = ((const uint4*)(S0 + (size_t)row * 128))[k8];
    }
    int wv = m >> 4, mr = m & 15, t = k8 >> 2, kq = k8 & 3;
    ((uint4*)sA)[(wv * 4 + t) * 64 + (kq * 16 + mr)] = v;
  }
  __syncthreads();

  const int w = tid >> 6, L = tid & 63;
  f32x4 acc[4];
#pragma unroll
  for (int i = 0; i < 4; ++i)
#pragma unroll
    for (int j = 0; j < 4; ++j) acc[i][j] = 0.f;

  const bf16x8* Af = (const bf16x8*)sA;
  const bf16x8* Bf = (const bf16x8*)Wp;
  const int nb = colOff >> 4;
#pragma unroll
  for (int t = 0; t < 4; ++t) {
    bf16x8 afr = Af[(w * 4 + t) * 64 + L];
#pragma unroll
    for (int n0 = 0; n0 < 4; ++n0) {
      bf16x8 bfr = Bf[((nb + n0) * 4 + t) * 64 + L];
      acc[n0] = __builtin_amdgcn_mfma_f32_16x16x32_bf16(afr, bfr, acc[n0], 0, 0, 0);
    }
  }
  __syncthreads();

  // ---- C frags -> LDS (row = w*16 + (L>>4)*4 + r, col = n0*16 + (L&15))
  {
    int rg = L >> 4, cl = L & 15;
#pragma unroll
    for (int n0 = 0; n0 < 4; ++n0)
#pragma unroll
      for (int r = 0; r < 4; ++r)
        sC[(w * 16 + rg * 4 + r) * 66 + n0 * 16 + cl] = acc[n0][r];
  }
  __syncthreads();

  // ---- coalesced bf16 write-out with bias/relu
#pragma unroll
  for (int it = 0; it < 2; ++it) {
    int c = tid + it * 256;    // 512 chunks of 8 cols
    int m = c >> 3, c8 = c & 7;
    int row = m0 + m;
    if (row < M) {
      float v[8];
#pragma unroll
      for (int j = 0; j < 8; ++j) v[j] = sC[m * 66 + c8 * 8 + j];
      if (bias) {
#pragma unroll
        for (int j = 0; j < 8; ++j) v[j] += bias[colOff + c8 * 8 + j];
      }
      if (doRelu) {
#pragma unroll
        for (int j = 0; j < 8; ++j) v[j] = fmaxf(v[j], 0.f);
      }
      uint4 o;
      o.x = packbf2(v[0], v[1]); o.y = packbf2(v[2], v[3]);
      o.z = packbf2(v[4], v[5]); o.w = packbf2(v[6], v[7]);
      ((uint4*)(OUT + (size_t)row * outStride + colOff))[c8] = o;
    }
  }
}

// ----------------------------------------------- fused mean-pool + MLP ------
__global__ __launch_bounds__(64) void k_poolmlp(
    const unsigned short* __restrict__ H, const int* __restrict__ gstart,
    const float* __restrict__ w1, const float* __restrict__ b1,
    const float* __restrict__ w2, const float* __restrict__ b2,
    const float* __restrict__ w3, const float* __restrict__ b3,
    const float* __restrict__ w4, const float* __restrict__ b4,
    float* __restrict__ out) {
  __shared__ float sg[64], s1[64], s2[32], s3[32];
  int g = blockIdx.x, t = threadIdx.x;
  int beg = gstart[g], end = gstart[g + 1];
  float acc = 0.0f;
#pragma unroll 4
  for (int n = beg; n < end; ++n) acc += bfs(H[(size_t)n * 64 + t]);
  float cnt = fmaxf((float)(end - beg), 1.0f);
  sg[t] = acc / cnt;
  __syncthreads();
  acc = b1[t];
  for (int k = 0; k < 64; ++k) acc += sg[k] * w1[k * 64 + t];
  s1[t] = fmaxf(acc, 0.0f);
  __syncthreads();
  if (t < 32) {
    acc = b2[t];
    for (int k = 0; k < 64; ++k) acc += s1[k] * w2[k * 32 + t];
    s2[t] = fmaxf(acc, 0.0f);
  }
  __syncthreads();
  if (t < 32) {
    acc = b3[t];
    for (int k = 0; k < 32; ++k) acc += s2[k] * w3[k * 32 + t];
    s3[t] = fmaxf(acc, 0.0f);
  }
  __syncthreads();
  if (t == 0) {
    acc = b4[0];
    for (int k = 0; k < 32; ++k) acc += s3[k] * w4[k];
    out[g] = acc;
  }
}

// ---------------------------------------------------------------- launch ----
extern "C" void kernel_launch(void* const* d_in, const int* in_sizes, int n_in,
                              void* d_out, int out_size, void* d_ws,
                              size_t ws_size, hipStream_t stream) {
  const float* x     = (const float*)d_in[0];
  const int*   ei    = (const int*)d_in[1];
  const int*   batch = (const int*)d_in[2];
  const int* src = ei;
  const int* dst = ei + NE;

  const float* c1_wl = (const float*)d_in[3];
  const float* c1_bl = (const float*)d_in[4];
  const float* c1_wr = (const float*)d_in[5];
  const float* c2_wl = (const float*)d_in[6];
  const float* c2_bl = (const float*)d_in[7];
  const float* c2_wr = (const float*)d_in[8];
  const float* c3_wl = (const float*)d_in[9];
  const float* c3_bl = (const float*)d_in[10];
  const float* c3_wr = (const float*)d_in[11];
  const float* c4_wl = (const float*)d_in[12];
  const float* c4_bl = (const float*)d_in[13];
  const float* c4_wr = (const float*)d_in[14];
  const float* l1w = (const float*)d_in[15];
  const float* l1b = (const float*)d_in[16];
  const float* l2w = (const float*)d_in[17];
  const float* l2b = (const float*)d_in[18];
  const float* l3w = (const float*)d_in[19];
  const float* l3b = (const float*)d_in[20];
  const float* l4w = (const float*)d_in[21];
  const float* l4b = (const float*)d_in[22];

  // ---- workspace carve-up (bf16 feature buffers, 16B-aligned offsets)
  char* wsb = (char*)d_ws;
  float* inv = (float*)wsb;                                   // NN fp32
  unsigned short* xb  = (unsigned short*)(wsb + (size_t)NN * 4);
  unsigned short* B1  = xb + (size_t)NN * 64;    // agg / h2 / h4
  unsigned short* B2  = B1 + (size_t)NN * 64;    // h1 (NN x 128)
  unsigned short* B3  = B2 + (size_t)NN * 128;
  unsigned short* B4  = B3 + (size_t)NN * 64;
  unsigned short* pL1  = B4 + (size_t)NN * 64;   // 128x128 pack
  unsigned short* pL2a = pL1 + 128 * 128;        // 128x64 packs
  unsigned short* pL2b = pL2a + 128 * 64;
  unsigned short* pL3  = pL2b + 128 * 64;
  unsigned short* pL4  = pL3 + 128 * 64;
  int* cnt    = (int*)(pL4 + 128 * 64);          // NN
  int* off    = cnt + NN;                        // NN+1
  int* bsum   = off + NN + 1;                    // 512
  int* gstart = bsum + 512;                      // NG+1
  int* csr    = gstart + NG + 1 + 2;             // NE
  int* rank   = csr + NE;                        // NE

  const int gE  = (NE + 255) / 256;   // 6250
  const int gN8 = NN * 8 / 256;       // 3125  (gather / cvt)
  const int gM  = (NN + 63) / 64;     // 1563  (gemm x)
  const int gN  = NBLK_SCAN;          // 391

  hipMemsetAsync(cnt, 0, (size_t)NN * 4, stream);

  // ---- CSR build + graph bounds + bf16 conversions/packing
  k_count<<<gE, 256, 0, stream>>>(dst, cnt, rank);
  k_scan1<<<gN, 256, 0, stream>>>(cnt, off, bsum);
  k_scan2<<<1, 512, 0, stream>>>(bsum);
  k_scan3<<<gN, 256, 0, stream>>>(off, bsum, cnt, inv);
  k_fill<<<dim3(gE, NPART), 256, 0, stream>>>(src, dst, off, rank, csr);
  k_bounds<<<5, 256, 0, stream>>>(batch, gstart);
  k_cvt<<<gN8, 256, 0, stream>>>(x, xb);
  k_prep<<<dim3(64, 5), 256, 0, stream>>>(c1_wl, c1_wr, c2_wl, c2_wr,
                                          c3_wl, c3_wr, c4_wl, c4_wr,
                                          pL1, pL2a, pL2b, pL3, pL4);

  // ---- layer 1: B2(h1) = relu([agg(x) | x] @ [[c1_wl],[c1_wr]] + c1_bl)
  k_gather<<<gN8, 256, 0, stream>>>(xb, csr, off, inv, nullptr, nullptr, B1);
  k_gemm<<<dim3(gM, 2), 256, 0, stream>>>(B1, xb, 1, pL1, 1, nullptr, nullptr,
                                          c1_bl, 1, B2, 128, NN);

  // ---- layer 2: B3 = h1@wl, B4 = h1@wr; B1(h2) = relu(agg(B3) + b + B4)
  k_gemm<<<dim3(gM, 2), 256, 0, stream>>>(B2, nullptr, 0, pL2a, 0, pL2b, B4,
                                          nullptr, 0, B3, 64, NN);
  k_gather<<<gN8, 256, 0, stream>>>(B3, csr, off, inv, c2_bl, B4, B1);

  // ---- layer 3: B4(h3) = relu([agg(h2) | h2] @ [[c3_wl],[c3_wr]] + c3_bl)
  k_gather<<<gN8, 256, 0, stream>>>(B1, csr, off, inv, nullptr, nullptr, B3);
  k_gemm<<<dim3(gM, 1), 256, 0, stream>>>(B3, B1, 1, pL3, 0, nullptr, nullptr,
                                          c3_bl, 1, B4, 64, NN);

  // ---- layer 4: B1(h4) = relu([agg(h3) | h3] @ [[c4_wl],[c4_wr]] + c4_bl)
  k_gather<<<gN8, 256, 0, stream>>>(B4, csr, off, inv, nullptr, nullptr, B3);
  k_gemm<<<dim3(gM, 1), 256, 0, stream>>>(B3, B4, 1, pL4, 0, nullptr, nullptr,
                                          c4_bl, 1, B1, 64, NN);

  // ---- fused pool + MLP
  k_poolmlp<<<NG, 64, 0, stream>>>(B1, gstart, l1w, l1b, l2w, l2b,
                                   l3w, l3b, l4w, l4b, (float*)d_out);
}

// Round 7
// 430.417 us; speedup vs baseline: 2.1520x; 1.0175x over previous
//
#include <hip/hip_runtime.h>

#define NN 100000
#define NE 1600000
#define NG 1024
#define NBLK_SCAN ((NN + 255) / 256)  // 391
#define NPART 4

// merged-setup grid layout
#define GB_COUNT 6250   // NE/256
#define GB_CVT   3125   // NN*64/8/256
#define GB_BND   5
#define GB_PREP  320    // 5 matrices x 64 blocks
#define GB_SETUP (GB_COUNT + GB_CVT + GB_BND + GB_PREP)

typedef __attribute__((ext_vector_type(8))) short bf16x8;
typedef __attribute__((ext_vector_type(4))) float f32x4;

__device__ __forceinline__ unsigned f2bf1(float f) {
  union { float f; unsigned u; } v; v.f = f;
  return (v.u + 0x7fffu + ((v.u >> 16) & 1u)) >> 16;  // RNE
}
__device__ __forceinline__ unsigned packbf2(float a, float b) {
  return f2bf1(a) | (f2bf1(b) << 16);
}
__device__ __forceinline__ float bflo(unsigned u) {
  union { unsigned u; float f; } v; v.u = u << 16; return v.f;
}
__device__ __forceinline__ float bfhi(unsigned u) {
  union { unsigned u; float f; } v; v.u = u & 0xffff0000u; return v.f;
}
__device__ __forceinline__ float bfs(unsigned short s) {
  union { unsigned u; float f; } v; v.u = ((unsigned)s) << 16; return v.f;
}

// ---------------------------------------------------------- merged setup ----
// count(atomic-latency-bound, pipes idle) + cvt + bounds + prep in ONE launch
__global__ __launch_bounds__(256) void k_setup(
    const int* __restrict__ dst, int* __restrict__ cnt, int* __restrict__ rank,
    const float* __restrict__ X, unsigned short* __restrict__ Xb,
    const int* __restrict__ batch, int* __restrict__ gstart,
    const float* __restrict__ c1wl, const float* __restrict__ c1wr,
    const float* __restrict__ c2wl, const float* __restrict__ c2wr,
    const float* __restrict__ c3wl, const float* __restrict__ c3wr,
    const float* __restrict__ c4wl, const float* __restrict__ c4wr,
    unsigned short* __restrict__ pL1, unsigned short* __restrict__ pL2a,
    unsigned short* __restrict__ pL2b, unsigned short* __restrict__ pL3,
    unsigned short* __restrict__ pL4) {
  int b = blockIdx.x, tid = threadIdx.x;
  if (b < GB_COUNT) {
    int e = b * 256 + tid;
    rank[e] = atomicAdd(&cnt[dst[e]], 1);
    return;
  }
  b -= GB_COUNT;
  if (b < GB_CVT) {
    int i = b * 256 + tid;  // 16B of bf16 out per thread
    const float4* p = (const float4*)X + (size_t)i * 2;
    float4 a = p[0], c = p[1];
    uint4 o;
    o.x = packbf2(a.x, a.y); o.y = packbf2(a.z, a.w);
    o.z = packbf2(c.x, c.y); o.w = packbf2(c.z, c.w);
    ((uint4*)Xb)[i] = o;
    return;
  }
  b -= GB_CVT;
  if (b < GB_BND) {
    int g = b * 256 + tid;
    if (g > NG) return;
    int lo = 0, hi = NN;
    while (lo < hi) {
      int mid = (lo + hi) >> 1;
      if (batch[mid] < g) lo = mid + 1; else hi = mid;
    }
    gstart[g] = lo;
    return;
  }
  b -= GB_BND;
  {
    int yb = b >> 6, xb = b & 63;
    const float *WL, *WR; unsigned short* dstp; int N;
    if (yb == 0)      { WL = c1wl; WR = c1wr;           dstp = pL1;  N = 128; }
    else if (yb == 1) { WL = c2wl; WR = c2wl + 64 * 64; dstp = pL2a; N = 64; }
    else if (yb == 2) { WL = c2wr; WR = c2wr + 64 * 64; dstp = pL2b; N = 64; }
    else if (yb == 3) { WL = c3wl; WR = c3wr;           dstp = pL3;  N = 64; }
    else              { WL = c4wl; WR = c4wr;           dstp = pL4;  N = 64; }
    int e = xb * 256 + tid;
    if (e >= 128 * N) return;
    int k = e / N, n = e - k * N;
    float w = (k < 64) ? WL[k * N + n] : WR[(k - 64) * N + n];
    int t = k >> 5, kq = (k >> 3) & 3, j = k & 7;
    int n0 = n >> 4, nl = n & 15;
    dstp[((((n0 * 4 + t) * 64) + (kq * 16 + nl)) << 3) + j] =
        (unsigned short)f2bf1(w);
  }
}

// ------------------------------------------------------------------ scans ---
__global__ __launch_bounds__(256) void k_scan1(const int* __restrict__ cnt,
                                               int* __restrict__ off,
                                               int* __restrict__ bsum) {
  __shared__ int s[256];
  int tid = threadIdx.x;
  int i = blockIdx.x * 256 + tid;
  int v = (i < NN) ? cnt[i] : 0;
  s[tid] = v;
  __syncthreads();
  for (int d = 1; d < 256; d <<= 1) {
    int t = (tid >= d) ? s[tid - d] : 0;
    __syncthreads();
    s[tid] += t;
    __syncthreads();
  }
  if (i < NN) off[i] = s[tid] - v;
  if (tid == 255) bsum[blockIdx.x] = s[255];
}

__global__ __launch_bounds__(512) void k_scan2(int* __restrict__ bsum) {
  __shared__ int s[512];
  int tid = threadIdx.x;
  int v = (tid < NBLK_SCAN) ? bsum[tid] : 0;
  s[tid] = v;
  __syncthreads();
  for (int d = 1; d < 512; d <<= 1) {
    int t = (tid >= d) ? s[tid - d] : 0;
    __syncthreads();
    s[tid] += t;
    __syncthreads();
  }
  if (tid < NBLK_SCAN) bsum[tid] = s[tid] - v;
}

__global__ __launch_bounds__(256) void k_scan3(int* __restrict__ off,
                                               const int* __restrict__ bsum,
                                               const int* __restrict__ cnt,
                                               float* __restrict__ inv) {
  int i = blockIdx.x * 256 + threadIdx.x;
  if (i < NN) {
    off[i] = off[i] + bsum[blockIdx.x];
    inv[i] = 1.0f / fmaxf((float)cnt[i], 1.0f);
  }
  if (i == 0) off[NN] = NE;
}

__global__ __launch_bounds__(256) void k_fill(const int* __restrict__ src,
                                              const int* __restrict__ dst,
                                              const int* __restrict__ off,
                                              const int* __restrict__ rank,
                                              int* __restrict__ csr) {
  int e = blockIdx.x * 256 + threadIdx.x;
  int lo = (int)blockIdx.y * (NN / NPART);
  int hi = lo + (NN / NPART);
  if (e < NE) {
    int d = dst[e];
    if (d >= lo && d < hi) csr[off[d] + rank[e]] = src[e];
  }
}

// --------------------------------------------------- gather (bf16 features) -
// 8 thr/node, 8 channels each (16B). 8-deep load pipeline, two accumulator
// banks (R6 was 4-deep; gathers are latency-bound on random 128B rows).
__global__ __launch_bounds__(256) void k_gather(
    const unsigned short* __restrict__ F, const int* __restrict__ csr,
    const int* __restrict__ off, const float* __restrict__ inv,
    const float* __restrict__ bias, const unsigned short* __restrict__ Z,
    unsigned short* __restrict__ out) {
  int idx = blockIdx.x * 256 + threadIdx.x;  // grid = NN*8 threads
  int n = idx >> 3, q = idx & 7;
  int beg = off[n], end = off[n + 1];
  float aA[8], aB[8];
#pragma unroll
  for (int c = 0; c < 8; ++c) { aA[c] = 0.f; aB[c] = 0.f; }
  int e = beg;
  for (; e + 8 <= end; e += 8) {
    uint4 v[8];
#pragma unroll
    for (int j = 0; j < 8; ++j)
      v[j] = ((const uint4*)(F + (size_t)csr[e + j] * 64))[q];
#pragma unroll
    for (int j = 0; j < 8; j += 2) {
      aA[0] += bflo(v[j].x); aB[0] += bflo(v[j + 1].x);
      aA[1] += bfhi(v[j].x); aB[1] += bfhi(v[j + 1].x);
      aA[2] += bflo(v[j].y); aB[2] += bflo(v[j + 1].y);
      aA[3] += bfhi(v[j].y); aB[3] += bfhi(v[j + 1].y);
      aA[4] += bflo(v[j].z); aB[4] += bflo(v[j + 1].z);
      aA[5] += bfhi(v[j].z); aB[5] += bfhi(v[j + 1].z);
      aA[6] += bflo(v[j].w); aB[6] += bflo(v[j + 1].w);
      aA[7] += bfhi(v[j].w); aB[7] += bfhi(v[j + 1].w);
    }
  }
  if (e + 4 <= end) {
    uint4 v[4];
#pragma unroll
    for (int j = 0; j < 4; ++j)
      v[j] = ((const uint4*)(F + (size_t)csr[e + j] * 64))[q];
#pragma unroll
    for (int j = 0; j < 4; j += 2) {
      aA[0] += bflo(v[j].x); aB[0] += bflo(v[j + 1].x);
      aA[1] += bfhi(v[j].x); aB[1] += bfhi(v[j + 1].x);
      aA[2] += bflo(v[j].y); aB[2] += bflo(v[j + 1].y);
      aA[3] += bfhi(v[j].y); aB[3] += bfhi(v[j + 1].y);
      aA[4] += bflo(v[j].z); aB[4] += bflo(v[j + 1].z);
      aA[5] += bfhi(v[j].z); aB[5] += bfhi(v[j + 1].z);
      aA[6] += bflo(v[j].w); aB[6] += bflo(v[j + 1].w);
      aA[7] += bfhi(v[j].w); aB[7] += bfhi(v[j + 1].w);
    }
    e += 4;
  }
  for (; e < end; ++e) {
    uint4 v0 = ((const uint4*)(F + (size_t)csr[e] * 64))[q];
    aA[0] += bflo(v0.x); aA[1] += bfhi(v0.x);
    aA[2] += bflo(v0.y); aA[3] += bfhi(v0.y);
    aA[4] += bflo(v0.z); aA[5] += bfhi(v0.z);
    aA[6] += bflo(v0.w); aA[7] += bfhi(v0.w);
  }
  float a[8];
  float iv = inv[n];
#pragma unroll
  for (int c = 0; c < 8; ++c) a[c] = (aA[c] + aB[c]) * iv;
  if (bias != nullptr) {  // layer-2 epilogue: relu(agg + bias + Z)
    uint4 z = ((const uint4*)(Z + (size_t)n * 64))[q];
    const float4* bp = (const float4*)(bias + q * 8);
    float4 b0 = bp[0], b1 = bp[1];
    a[0] = fmaxf(a[0] + b0.x + bflo(z.x), 0.f);
    a[1] = fmaxf(a[1] + b0.y + bfhi(z.x), 0.f);
    a[2] = fmaxf(a[2] + b0.z + bflo(z.y), 0.f);
    a[3] = fmaxf(a[3] + b0.w + bfhi(z.y), 0.f);
    a[4] = fmaxf(a[4] + b1.x + bflo(z.z), 0.f);
    a[5] = fmaxf(a[5] + b1.y + bfhi(z.z), 0.f);
    a[6] = fmaxf(a[6] + b1.z + bflo(z.w), 0.f);
    a[7] = fmaxf(a[7] + b1.w + bfhi(z.w), 0.f);
  }
  uint4 o;
  o.x = packbf2(a[0], a[1]); o.y = packbf2(a[2], a[3]);
  o.z = packbf2(a[4], a[5]); o.w = packbf2(a[6], a[7]);
  ((uint4*)(out + (size_t)n * 64))[q] = o;
}

// ------------------------------------------------------------ MFMA GEMM -----
__global__ __launch_bounds__(256) void k_gemm(
    const unsigned short* __restrict__ S0, const unsigned short* __restrict__ S1,
    int dual,
    const unsigned short* __restrict__ Wp, int colMulY,
    const unsigned short* __restrict__ Wp2, unsigned short* __restrict__ OUT2,
    const float* __restrict__ bias, int doRelu,
    unsigned short* __restrict__ OUT, int outStride, int M) {
  __shared__ __align__(16) char smem[64 * 66 * 4];  // sA 16384B / sC 16896B
  unsigned short* sA = (unsigned short*)smem;
  float* sC = (float*)smem;
  const int tid = threadIdx.x;

  int colOff = 0;
  if (colMulY) colOff = 64 * blockIdx.y;
  else if (blockIdx.y == 1) { Wp = Wp2; OUT = OUT2; }

  const int m0 = blockIdx.x * 64;

  // ---- stage A (64 rows x 128 k) into A-frag order
#pragma unroll
  for (int l = 0; l < 4; ++l) {
    int c = tid + l * 256;     // 1024 chunks of bf16x8
    int m = c >> 4, k8 = c & 15;
    int row = m0 + m;
    uint4 v = make_uint4(0, 0, 0, 0);
    if (row < M) {
      if (dual)
        v = (k8 < 8) ? ((const uint4*)(S0 + (size_t)row * 64))[k8]
                     : ((const uint4*)(S1 + (size_t)row * 64))[k8 - 8];
      else
        v = ((const uint4*)(S0 + (size_t)row * 128))[k8];
    }
    int wv = m >> 4, mr = m & 15, t = k8 >> 2, kq = k8 & 3;
    ((uint4*)sA)[(wv * 4 + t) * 64 + (kq * 16 + mr)] = v;
  }
  __syncthreads();

  const int w = tid >> 6, L = tid & 63;
  f32x4 acc[4];
#pragma unroll
  for (int i = 0; i < 4; ++i)
#pragma unroll
    for (int j = 0; j < 4; ++j) acc[i][j] = 0.f;

  const bf16x8* Af = (const bf16x8*)sA;
  const bf16x8* Bf = (const bf16x8*)Wp;
  const int nb = colOff >> 4;
#pragma unroll
  for (int t = 0; t < 4; ++t) {
    bf16x8 afr = Af[(w * 4 + t) * 64 + L];
#pragma unroll
    for (int n0 = 0; n0 < 4; ++n0) {
      bf16x8 bfr = Bf[((nb + n0) * 4 + t) * 64 + L];
      acc[n0] = __builtin_amdgcn_mfma_f32_16x16x32_bf16(afr, bfr, acc[n0], 0, 0, 0);
    }
  }
  __syncthreads();

  // ---- C frags -> LDS (row = w*16 + (L>>4)*4 + r, col = n0*16 + (L&15))
  {
    int rg = L >> 4, cl = L & 15;
#pragma unroll
    for (int n0 = 0; n0 < 4; ++n0)
#pragma unroll
      for (int r = 0; r < 4; ++r)
        sC[(w * 16 + rg * 4 + r) * 66 + n0 * 16 + cl] = acc[n0][r];
  }
  __syncthreads();

  // ---- coalesced bf16 write-out with bias/relu
#pragma unroll
  for (int it = 0; it < 2; ++it) {
    int c = tid + it * 256;    // 512 chunks of 8 cols
    int m = c >> 3, c8 = c & 7;
    int row = m0 + m;
    if (row < M) {
      float v[8];
#pragma unroll
      for (int j = 0; j < 8; ++j) v[j] = sC[m * 66 + c8 * 8 + j];
      if (bias) {
#pragma unroll
        for (int j = 0; j < 8; ++j) v[j] += bias[colOff + c8 * 8 + j];
      }
      if (doRelu) {
#pragma unroll
        for (int j = 0; j < 8; ++j) v[j] = fmaxf(v[j], 0.f);
      }
      uint4 o;
      o.x = packbf2(v[0], v[1]); o.y = packbf2(v[2], v[3]);
      o.z = packbf2(v[4], v[5]); o.w = packbf2(v[6], v[7]);
      ((uint4*)(OUT + (size_t)row * outStride + colOff))[c8] = o;
    }
  }
}

// ----------------------------------------------- fused mean-pool + MLP ------
__global__ __launch_bounds__(64) void k_poolmlp(
    const unsigned short* __restrict__ H, const int* __restrict__ gstart,
    const float* __restrict__ w1, const float* __restrict__ b1,
    const float* __restrict__ w2, const float* __restrict__ b2,
    const float* __restrict__ w3, const float* __restrict__ b3,
    const float* __restrict__ w4, const float* __restrict__ b4,
    float* __restrict__ out) {
  __shared__ float sg[64], s1[64], s2[32], s3[32];
  int g = blockIdx.x, t = threadIdx.x;
  int beg = gstart[g], end = gstart[g + 1];
  float acc = 0.0f;
#pragma unroll 4
  for (int n = beg; n < end; ++n) acc += bfs(H[(size_t)n * 64 + t]);
  float cnt = fmaxf((float)(end - beg), 1.0f);
  sg[t] = acc / cnt;
  __syncthreads();
  acc = b1[t];
  for (int k = 0; k < 64; ++k) acc += sg[k] * w1[k * 64 + t];
  s1[t] = fmaxf(acc, 0.0f);
  __syncthreads();
  if (t < 32) {
    acc = b2[t];
    for (int k = 0; k < 64; ++k) acc += s1[k] * w2[k * 32 + t];
    s2[t] = fmaxf(acc, 0.0f);
  }
  __syncthreads();
  if (t < 32) {
    acc = b3[t];
    for (int k = 0; k < 32; ++k) acc += s2[k] * w3[k * 32 + t];
    s3[t] = fmaxf(acc, 0.0f);
  }
  __syncthreads();
  if (t == 0) {
    acc = b4[0];
    for (int k = 0; k < 32; ++k) acc += s3[k] * w4[k];
    out[g] = acc;
  }
}

// ---------------------------------------------------------------- launch ----
extern "C" void kernel_launch(void* const* d_in, const int* in_sizes, int n_in,
                              void* d_out, int out_size, void* d_ws,
                              size_t ws_size, hipStream_t stream) {
  const float* x     = (const float*)d_in[0];
  const int*   ei    = (const int*)d_in[1];
  const int*   batch = (const int*)d_in[2];
  const int* src = ei;
  const int* dst = ei + NE;

  const float* c1_wl = (const float*)d_in[3];
  const float* c1_bl = (const float*)d_in[4];
  const float* c1_wr = (const float*)d_in[5];
  const float* c2_wl = (const float*)d_in[6];
  const float* c2_bl = (const float*)d_in[7];
  const float* c2_wr = (const float*)d_in[8];
  const float* c3_wl = (const float*)d_in[9];
  const float* c3_bl = (const float*)d_in[10];
  const float* c3_wr = (const float*)d_in[11];
  const float* c4_wl = (const float*)d_in[12];
  const float* c4_bl = (const float*)d_in[13];
  const float* c4_wr = (const float*)d_in[14];
  const float* l1w = (const float*)d_in[15];
  const float* l1b = (const float*)d_in[16];
  const float* l2w = (const float*)d_in[17];
  const float* l2b = (const float*)d_in[18];
  const float* l3w = (const float*)d_in[19];
  const float* l3b = (const float*)d_in[20];
  const float* l4w = (const float*)d_in[21];
  const float* l4b = (const float*)d_in[22];

  // ---- workspace carve-up (bf16 feature buffers, 16B-aligned offsets)
  char* wsb = (char*)d_ws;
  float* inv = (float*)wsb;                                   // NN fp32
  unsigned short* xb  = (unsigned short*)(wsb + (size_t)NN * 4);
  unsigned short* B1  = xb + (size_t)NN * 64;    // agg / h2 / h4
  unsigned short* B2  = B1 + (size_t)NN * 64;    // h1 (NN x 128)
  unsigned short* B3  = B2 + (size_t)NN * 128;
  unsigned short* B4  = B3 + (size_t)NN * 64;
  unsigned short* pL1  = B4 + (size_t)NN * 64;   // 128x128 pack
  unsigned short* pL2a = pL1 + 128 * 128;        // 128x64 packs
  unsigned short* pL2b = pL2a + 128 * 64;
  unsigned short* pL3  = pL2b + 128 * 64;
  unsigned short* pL4  = pL3 + 128 * 64;
  int* cnt    = (int*)(pL4 + 128 * 64);          // NN
  int* off    = cnt + NN;                        // NN+1
  int* bsum   = off + NN + 1;                    // 512
  int* gstart = bsum + 512;                      // NG+1
  int* csr    = gstart + NG + 1 + 2;             // NE
  int* rank   = csr + NE;                        // NE

  const int gE  = (NE + 255) / 256;   // 6250
  const int gN8 = NN * 8 / 256;       // 3125  (gather)
  const int gM  = (NN + 63) / 64;     // 1563  (gemm x)
  const int gN  = NBLK_SCAN;          // 391

  hipMemsetAsync(cnt, 0, (size_t)NN * 4, stream);

  // ---- merged setup: count + cvt + bounds + weight-pack in one launch
  k_setup<<<GB_SETUP, 256, 0, stream>>>(dst, cnt, rank, x, xb, batch, gstart,
                                        c1_wl, c1_wr, c2_wl, c2_wr,
                                        c3_wl, c3_wr, c4_wl, c4_wr,
                                        pL1, pL2a, pL2b, pL3, pL4);
  k_scan1<<<gN, 256, 0, stream>>>(cnt, off, bsum);
  k_scan2<<<1, 512, 0, stream>>>(bsum);
  k_scan3<<<gN, 256, 0, stream>>>(off, bsum, cnt, inv);
  k_fill<<<dim3(gE, NPART), 256, 0, stream>>>(src, dst, off, rank, csr);

  // ---- layer 1: B2(h1) = relu([agg(x) | x] @ [[c1_wl],[c1_wr]] + c1_bl)
  k_gather<<<gN8, 256, 0, stream>>>(xb, csr, off, inv, nullptr, nullptr, B1);
  k_gemm<<<dim3(gM, 2), 256, 0, stream>>>(B1, xb, 1, pL1, 1, nullptr, nullptr,
                                          c1_bl, 1, B2, 128, NN);

  // ---- layer 2: B3 = h1@wl, B4 = h1@wr; B1(h2) = relu(agg(B3) + b + B4)
  k_gemm<<<dim3(gM, 2), 256, 0, stream>>>(B2, nullptr, 0, pL2a, 0, pL2b, B4,
                                          nullptr, 0, B3, 64, NN);
  k_gather<<<gN8, 256, 0, stream>>>(B3, csr, off, inv, c2_bl, B4, B1);

  // ---- layer 3: B4(h3) = relu([agg(h2) | h2] @ [[c3_wl],[c3_wr]] + c3_bl)
  k_gather<<<gN8, 256, 0, stream>>>(B1, csr, off, inv, nullptr, nullptr, B3);
  k_gemm<<<dim3(gM, 1), 256, 0, stream>>>(B3, B1, 1, pL3, 0, nullptr, nullptr,
                                          c3_bl, 1, B4, 64, NN);

  // ---- layer 4: B1(h4) = relu([agg(h3) | h3] @ [[c4_wl],[c4_wr]] + c4_bl)
  k_gather<<<gN8, 256, 0, stream>>>(B4, csr, off, inv, nullptr, nullptr, B3);
  k_gemm<<<dim3(gM, 1), 256, 0, stream>>>(B3, B4, 1, pL4, 0, nullptr, nullptr,
                                          c4_bl, 1, B1, 64, NN);

  // ---- fused pool + MLP
  k_poolmlp<<<NG, 64, 0, stream>>>(B1, gstart, l1w, l1b, l2w, l2b,
                                   l3w, l3b, l4w, l4b, (float*)d_out);
}

// Round 8
// 410.677 us; speedup vs baseline: 2.2555x; 1.0481x over previous
//
#include <hip/hip_runtime.h>

#define NN 100000
#define NE 1600000
#define NG 1024
#define NBLK_SCAN ((NN + 255) / 256)  // 391
#define NPART 4

// merged-setup grid layout
#define GB_COUNT 6250   // NE/256
#define GB_CVT   3125   // NN*64/8/256
#define GB_BND   5
#define GB_PREP  320    // 5 matrices x 64 blocks
#define GB_SETUP (GB_COUNT + GB_CVT + GB_BND + GB_PREP)

typedef __attribute__((ext_vector_type(8))) short bf16x8;
typedef __attribute__((ext_vector_type(4))) float f32x4;

__device__ __forceinline__ unsigned f2bf1(float f) {
  union { float f; unsigned u; } v; v.f = f;
  return (v.u + 0x7fffu + ((v.u >> 16) & 1u)) >> 16;  // RNE
}
__device__ __forceinline__ unsigned packbf2(float a, float b) {
  return f2bf1(a) | (f2bf1(b) << 16);
}
__device__ __forceinline__ float bflo(unsigned u) {
  union { unsigned u; float f; } v; v.u = u << 16; return v.f;
}
__device__ __forceinline__ float bfhi(unsigned u) {
  union { unsigned u; float f; } v; v.u = u & 0xffff0000u; return v.f;
}
__device__ __forceinline__ float bfs(unsigned short s) {
  union { unsigned u; float f; } v; v.u = ((unsigned)s) << 16; return v.f;
}

// ---------------------------------------------------------- merged setup ----
__global__ __launch_bounds__(256) void k_setup(
    const int* __restrict__ dst, int* __restrict__ cnt, int* __restrict__ rank,
    const float* __restrict__ X, unsigned short* __restrict__ Xb,
    const int* __restrict__ batch, int* __restrict__ gstart,
    const float* __restrict__ c1wl, const float* __restrict__ c1wr,
    const float* __restrict__ c2wl, const float* __restrict__ c2wr,
    const float* __restrict__ c3wl, const float* __restrict__ c3wr,
    const float* __restrict__ c4wl, const float* __restrict__ c4wr,
    unsigned short* __restrict__ pL1, unsigned short* __restrict__ pL2a,
    unsigned short* __restrict__ pL2b, unsigned short* __restrict__ pL3,
    unsigned short* __restrict__ pL4) {
  int b = blockIdx.x, tid = threadIdx.x;
  if (b < GB_COUNT) {
    int e = b * 256 + tid;
    rank[e] = atomicAdd(&cnt[dst[e]], 1);
    return;
  }
  b -= GB_COUNT;
  if (b < GB_CVT) {
    int i = b * 256 + tid;
    const float4* p = (const float4*)X + (size_t)i * 2;
    float4 a = p[0], c = p[1];
    uint4 o;
    o.x = packbf2(a.x, a.y); o.y = packbf2(a.z, a.w);
    o.z = packbf2(c.x, c.y); o.w = packbf2(c.z, c.w);
    ((uint4*)Xb)[i] = o;
    return;
  }
  b -= GB_CVT;
  if (b < GB_BND) {
    int g = b * 256 + tid;
    if (g > NG) return;
    int lo = 0, hi = NN;
    while (lo < hi) {
      int mid = (lo + hi) >> 1;
      if (batch[mid] < g) lo = mid + 1; else hi = mid;
    }
    gstart[g] = lo;
    return;
  }
  b -= GB_BND;
  {
    int yb = b >> 6, xb = b & 63;
    const float *WL, *WR; unsigned short* dstp; int N;
    if (yb == 0)      { WL = c1wl; WR = c1wr;           dstp = pL1;  N = 128; }
    else if (yb == 1) { WL = c2wl; WR = c2wl + 64 * 64; dstp = pL2a; N = 64; }
    else if (yb == 2) { WL = c2wr; WR = c2wr + 64 * 64; dstp = pL2b; N = 64; }
    else if (yb == 3) { WL = c3wl; WR = c3wr;           dstp = pL3;  N = 64; }
    else              { WL = c4wl; WR = c4wr;           dstp = pL4;  N = 64; }
    int e = xb * 256 + tid;
    if (e >= 128 * N) return;
    int k = e / N, n = e - k * N;
    float w = (k < 64) ? WL[k * N + n] : WR[(k - 64) * N + n];
    int t = k >> 5, kq = (k >> 3) & 3, j = k & 7;
    int n0 = n >> 4, nl = n & 15;
    dstp[((((n0 * 4 + t) * 64) + (kq * 16 + nl)) << 3) + j] =
        (unsigned short)f2bf1(w);
  }
}

// ------------------------------------------------------------------ scans ---
__global__ __launch_bounds__(256) void k_scan1(const int* __restrict__ cnt,
                                               int* __restrict__ off,
                                               int* __restrict__ bsum) {
  __shared__ int s[256];
  int tid = threadIdx.x;
  int i = blockIdx.x * 256 + tid;
  int v = (i < NN) ? cnt[i] : 0;
  s[tid] = v;
  __syncthreads();
  for (int d = 1; d < 256; d <<= 1) {
    int t = (tid >= d) ? s[tid - d] : 0;
    __syncthreads();
    s[tid] += t;
    __syncthreads();
  }
  if (i < NN) off[i] = s[tid] - v;
  if (tid == 255) bsum[blockIdx.x] = s[255];
}

// scan stages 2+3 merged: each block redundantly sums bsum[j < blockIdx.x]
// (<=391 ints, coalesced) -> no inter-block dependency. + invdeg fused.
__global__ __launch_bounds__(256) void k_scan23(int* __restrict__ off,
                                                const int* __restrict__ bsum,
                                                const int* __restrict__ cnt,
                                                float* __restrict__ inv) {
  __shared__ int red[256];
  int b = blockIdx.x, tid = threadIdx.x;
  int s = 0;
  for (int j = tid; j < b; j += 256) s += bsum[j];
  red[tid] = s;
  __syncthreads();
  for (int d = 128; d > 0; d >>= 1) {
    if (tid < d) red[tid] += red[tid + d];
    __syncthreads();
  }
  int base = red[0];
  int i = b * 256 + tid;
  if (i < NN) {
    off[i] = off[i] + base;
    inv[i] = 1.0f / fmaxf((float)cnt[i], 1.0f);
  }
  if (i == 0) off[NN] = NE;
}

__global__ __launch_bounds__(256) void k_fill(const int* __restrict__ src,
                                              const int* __restrict__ dst,
                                              const int* __restrict__ off,
                                              const int* __restrict__ rank,
                                              int* __restrict__ csr) {
  int e = blockIdx.x * 256 + threadIdx.x;
  int lo = (int)blockIdx.y * (NN / NPART);
  int hi = lo + (NN / NPART);
  if (e < NE) {
    int d = dst[e];
    if (d >= lo && d < hi) csr[off[d] + rank[e]] = src[e];
  }
}

// ---------------------------- gather (layer-2 epilogue only: relu(agg+b+Z)) -
__global__ __launch_bounds__(256) void k_gather(
    const unsigned short* __restrict__ F, const int* __restrict__ csr,
    const int* __restrict__ off, const float* __restrict__ inv,
    const float* __restrict__ bias, const unsigned short* __restrict__ Z,
    unsigned short* __restrict__ out) {
  int idx = blockIdx.x * 256 + threadIdx.x;  // grid = NN*8 threads
  int n = idx >> 3, q = idx & 7;
  int beg = off[n], end = off[n + 1];
  float aA[8], aB[8];
#pragma unroll
  for (int c = 0; c < 8; ++c) { aA[c] = 0.f; aB[c] = 0.f; }
  int e = beg;
  for (; e + 4 <= end; e += 4) {
    uint4 v[4];
#pragma unroll
    for (int j = 0; j < 4; ++j)
      v[j] = ((const uint4*)(F + (size_t)csr[e + j] * 64))[q];
#pragma unroll
    for (int j = 0; j < 4; j += 2) {
      aA[0] += bflo(v[j].x); aB[0] += bflo(v[j + 1].x);
      aA[1] += bfhi(v[j].x); aB[1] += bfhi(v[j + 1].x);
      aA[2] += bflo(v[j].y); aB[2] += bflo(v[j + 1].y);
      aA[3] += bfhi(v[j].y); aB[3] += bfhi(v[j + 1].y);
      aA[4] += bflo(v[j].z); aB[4] += bflo(v[j + 1].z);
      aA[5] += bfhi(v[j].z); aB[5] += bfhi(v[j + 1].z);
      aA[6] += bflo(v[j].w); aB[6] += bflo(v[j + 1].w);
      aA[7] += bfhi(v[j].w); aB[7] += bfhi(v[j + 1].w);
    }
  }
  for (; e < end; ++e) {
    uint4 v0 = ((const uint4*)(F + (size_t)csr[e] * 64))[q];
    aA[0] += bflo(v0.x); aA[1] += bfhi(v0.x);
    aA[2] += bflo(v0.y); aA[3] += bfhi(v0.y);
    aA[4] += bflo(v0.z); aA[5] += bfhi(v0.z);
    aA[6] += bflo(v0.w); aA[7] += bfhi(v0.w);
  }
  float a[8];
  float iv = inv[n];
#pragma unroll
  for (int c = 0; c < 8; ++c) a[c] = (aA[c] + aB[c]) * iv;
  {
    uint4 z = ((const uint4*)(Z + (size_t)n * 64))[q];
    const float4* bp = (const float4*)(bias + q * 8);
    float4 b0 = bp[0], b1 = bp[1];
    a[0] = fmaxf(a[0] + b0.x + bflo(z.x), 0.f);
    a[1] = fmaxf(a[1] + b0.y + bfhi(z.x), 0.f);
    a[2] = fmaxf(a[2] + b0.z + bflo(z.y), 0.f);
    a[3] = fmaxf(a[3] + b0.w + bfhi(z.y), 0.f);
    a[4] = fmaxf(a[4] + b1.x + bflo(z.z), 0.f);
    a[5] = fmaxf(a[5] + b1.y + bfhi(z.z), 0.f);
    a[6] = fmaxf(a[6] + b1.z + bflo(z.w), 0.f);
    a[7] = fmaxf(a[7] + b1.w + bfhi(z.w), 0.f);
  }
  uint4 o;
  o.x = packbf2(a[0], a[1]); o.y = packbf2(a[2], a[3]);
  o.z = packbf2(a[4], a[5]); o.w = packbf2(a[6], a[7]);
  ((uint4*)(out + (size_t)n * 64))[q] = o;
}

// ------------------------------------------- fused gather + MFMA GEMM -------
// OUT[64 rows x NF*16 cols] = relu([agg(F) | F] @ Wp + bias)
// Each block gathers its own 64 rows' neighbor-means straight into the LDS
// A-frag buffer (K-half 0), stages its own F rows as K-half 1, then MFMAs.
// agg never touches global memory; gather phase of block b+1 overlaps MFMA
// of block b on the same CU.
template <int NF>  // 8 (128 cols) or 4 (64 cols)
__global__ __launch_bounds__(256, 4) void k_fgemm(
    const unsigned short* __restrict__ F, const int* __restrict__ csr,
    const int* __restrict__ off, const float* __restrict__ inv,
    const unsigned short* __restrict__ Wp, const float* __restrict__ bias,
    unsigned short* __restrict__ OUT, int outStride) {
  __shared__ __align__(16) char smem[64 * 66 * 4];  // sA 16384B / sC 16896B
  unsigned short* sA = (unsigned short*)smem;
  float* sC = (float*)smem;
  const int tid = threadIdx.x;
  const int m0 = blockIdx.x * 64;

  // ---- phase A: gather-aggregate into A-frag K-half 0 (k8 0..7)
  {
    int m = tid >> 2, qr = tid & 3;  // 4 threads/node, 16 channels each
    int row = m0 + m;
    float a0[16], a1[16];
#pragma unroll
    for (int c = 0; c < 16; ++c) { a0[c] = 0.f; a1[c] = 0.f; }
    if (row < NN) {
      int beg = off[row], end = off[row + 1];
      int e = beg;
      for (; e + 2 <= end; e += 2) {
        int s0 = csr[e], s1 = csr[e + 1];
        const uint4* r0 = (const uint4*)(F + (size_t)s0 * 64) + qr * 2;
        const uint4* r1 = (const uint4*)(F + (size_t)s1 * 64) + qr * 2;
        uint4 p0 = r0[0], p1 = r0[1], q0 = r1[0], q1 = r1[1];
        a0[0] += bflo(p0.x); a0[1] += bfhi(p0.x);
        a0[2] += bflo(p0.y); a0[3] += bfhi(p0.y);
        a0[4] += bflo(p0.z); a0[5] += bfhi(p0.z);
        a0[6] += bflo(p0.w); a0[7] += bfhi(p0.w);
        a0[8] += bflo(p1.x); a0[9] += bfhi(p1.x);
        a0[10] += bflo(p1.y); a0[11] += bfhi(p1.y);
        a0[12] += bflo(p1.z); a0[13] += bfhi(p1.z);
        a0[14] += bflo(p1.w); a0[15] += bfhi(p1.w);
        a1[0] += bflo(q0.x); a1[1] += bfhi(q0.x);
        a1[2] += bflo(q0.y); a1[3] += bfhi(q0.y);
        a1[4] += bflo(q0.z); a1[5] += bfhi(q0.z);
        a1[6] += bflo(q0.w); a1[7] += bfhi(q0.w);
        a1[8] += bflo(q1.x); a1[9] += bfhi(q1.x);
        a1[10] += bflo(q1.y); a1[11] += bfhi(q1.y);
        a1[12] += bflo(q1.z); a1[13] += bfhi(q1.z);
        a1[14] += bflo(q1.w); a1[15] += bfhi(q1.w);
      }
      if (e < end) {
        const uint4* r0 = (const uint4*)(F + (size_t)csr[e] * 64) + qr * 2;
        uint4 p0 = r0[0], p1 = r0[1];
        a0[0] += bflo(p0.x); a0[1] += bfhi(p0.x);
        a0[2] += bflo(p0.y); a0[3] += bfhi(p0.y);
        a0[4] += bflo(p0.z); a0[5] += bfhi(p0.z);
        a0[6] += bflo(p0.w); a0[7] += bfhi(p0.w);
        a0[8] += bflo(p1.x); a0[9] += bfhi(p1.x);
        a0[10] += bflo(p1.y); a0[11] += bfhi(p1.y);
        a0[12] += bflo(p1.z); a0[13] += bfhi(p1.z);
        a0[14] += bflo(p1.w); a0[15] += bfhi(p1.w);
      }
      float iv = inv[row];
#pragma unroll
      for (int c = 0; c < 16; ++c) a0[c] = (a0[c] + a1[c]) * iv;
    } else {
#pragma unroll
      for (int c = 0; c < 16; ++c) a0[c] = 0.f;
    }
    int wv = m >> 4, mr = m & 15;
#pragma unroll
    for (int h = 0; h < 2; ++h) {
      int k8 = qr * 2 + h;             // 0..7
      int t = k8 >> 2, kq = k8 & 3;
      uint4 o;
      o.x = packbf2(a0[h * 8 + 0], a0[h * 8 + 1]);
      o.y = packbf2(a0[h * 8 + 2], a0[h * 8 + 3]);
      o.z = packbf2(a0[h * 8 + 4], a0[h * 8 + 5]);
      o.w = packbf2(a0[h * 8 + 6], a0[h * 8 + 7]);
      ((uint4*)sA)[(wv * 4 + t) * 64 + kq * 16 + mr] = o;
    }
  }
  // ---- phase B: stage own rows as K-half 1 (k8 8..15)
#pragma unroll
  for (int l = 0; l < 2; ++l) {
    int c = tid + l * 256;  // 512 chunks: m(64) x j(8)
    int m = c >> 3, j = c & 7;
    int row = m0 + m;
    uint4 v = make_uint4(0, 0, 0, 0);
    if (row < NN) v = ((const uint4*)(F + (size_t)row * 64))[j];
    int k8 = 8 + j, t = k8 >> 2, kq = k8 & 3;
    int wv = m >> 4, mr = m & 15;
    ((uint4*)sA)[(wv * 4 + t) * 64 + kq * 16 + mr] = v;
  }
  __syncthreads();

  const int w = tid >> 6, L = tid & 63;
  const bf16x8* Af = (const bf16x8*)sA;
  const bf16x8* Bf = (const bf16x8*)Wp;
  f32x4 acc[NF];
#pragma unroll
  for (int i = 0; i < NF; ++i)
#pragma unroll
    for (int j = 0; j < 4; ++j) acc[i][j] = 0.f;
#pragma unroll
  for (int t = 0; t < 4; ++t) {
    bf16x8 afr = Af[(w * 4 + t) * 64 + L];
#pragma unroll
    for (int n0 = 0; n0 < NF; ++n0) {
      bf16x8 bfr = Bf[(n0 * 4 + t) * 64 + L];
      acc[n0] = __builtin_amdgcn_mfma_f32_16x16x32_bf16(afr, bfr, acc[n0], 0, 0, 0);
    }
  }

  // ---- epilogue in rounds of 64 cols (sC reuses sA space)
  int rg = L >> 4, cl = L & 15;
#pragma unroll
  for (int half = 0; half < NF / 4; ++half) {
    __syncthreads();
#pragma unroll
    for (int n0 = 0; n0 < 4; ++n0)
#pragma unroll
      for (int r = 0; r < 4; ++r)
        sC[(w * 16 + rg * 4 + r) * 66 + n0 * 16 + cl] = acc[half * 4 + n0][r];
    __syncthreads();
#pragma unroll
    for (int it = 0; it < 2; ++it) {
      int c = tid + it * 256;
      int m = c >> 3, c8 = c & 7;
      int row = m0 + m;
      if (row < NN) {
        float v[8];
#pragma unroll
        for (int j = 0; j < 8; ++j)
          v[j] = fmaxf(sC[m * 66 + c8 * 8 + j] + bias[half * 64 + c8 * 8 + j], 0.f);
        uint4 o;
        o.x = packbf2(v[0], v[1]); o.y = packbf2(v[2], v[3]);
        o.z = packbf2(v[4], v[5]); o.w = packbf2(v[6], v[7]);
        ((uint4*)(OUT + (size_t)row * outStride + half * 64))[c8] = o;
      }
    }
  }
}

// ------------------------------------------------------------ MFMA GEMM -----
// (layer 2 only: h1 @ wl -> OUT, h1 @ wr -> OUT2, no bias/relu)
__global__ __launch_bounds__(256) void k_gemm(
    const unsigned short* __restrict__ S0,
    const unsigned short* __restrict__ Wp,
    const unsigned short* __restrict__ Wp2, unsigned short* __restrict__ OUT2,
    unsigned short* __restrict__ OUT, int M) {
  __shared__ __align__(16) char smem[64 * 66 * 4];
  unsigned short* sA = (unsigned short*)smem;
  float* sC = (float*)smem;
  const int tid = threadIdx.x;
  if (blockIdx.y == 1) { Wp = Wp2; OUT = OUT2; }
  const int m0 = blockIdx.x * 64;

#pragma unroll
  for (int l = 0; l < 4; ++l) {
    int c = tid + l * 256;
    int m = c >> 4, k8 = c & 15;
    int row = m0 + m;
    uint4 v = make_uint4(0, 0, 0, 0);
    if (row < M) v = ((const uint4*)(S0 + (size_t)row * 128))[k8];
    int wv = m >> 4, mr = m & 15, t = k8 >> 2, kq = k8 & 3;
    ((uint4*)sA)[(wv * 4 + t) * 64 + (kq * 16 + mr)] = v;
  }
  __syncthreads();

  const int w = tid >> 6, L = tid & 63;
  f32x4 acc[4];
#pragma unroll
  for (int i = 0; i < 4; ++i)
#pragma unroll
    for (int j = 0; j < 4; ++j) acc[i][j] = 0.f;

  const bf16x8* Af = (const bf16x8*)sA;
  const bf16x8* Bf = (const bf16x8*)Wp;
#pragma unroll
  for (int t = 0; t < 4; ++t) {
    bf16x8 afr = Af[(w * 4 + t) * 64 + L];
#pragma unroll
    for (int n0 = 0; n0 < 4; ++n0) {
      bf16x8 bfr = Bf[(n0 * 4 + t) * 64 + L];
      acc[n0] = __builtin_amdgcn_mfma_f32_16x16x32_bf16(afr, bfr, acc[n0], 0, 0, 0);
    }
  }
  __syncthreads();
  {
    int rg = L >> 4, cl = L & 15;
#pragma unroll
    for (int n0 = 0; n0 < 4; ++n0)
#pragma unroll
      for (int r = 0; r < 4; ++r)
        sC[(w * 16 + rg * 4 + r) * 66 + n0 * 16 + cl] = acc[n0][r];
  }
  __syncthreads();
#pragma unroll
  for (int it = 0; it < 2; ++it) {
    int c = tid + it * 256;
    int m = c >> 3, c8 = c & 7;
    int row = m0 + m;
    if (row < M) {
      float v[8];
#pragma unroll
      for (int j = 0; j < 8; ++j) v[j] = sC[m * 66 + c8 * 8 + j];
      uint4 o;
      o.x = packbf2(v[0], v[1]); o.y = packbf2(v[2], v[3]);
      o.z = packbf2(v[4], v[5]); o.w = packbf2(v[6], v[7]);
      ((uint4*)(OUT + (size_t)row * 64))[c8] = o;
    }
  }
}

// ----------------------------------------------- fused mean-pool + MLP ------
__global__ __launch_bounds__(64) void k_poolmlp(
    const unsigned short* __restrict__ H, const int* __restrict__ gstart,
    const float* __restrict__ w1, const float* __restrict__ b1,
    const float* __restrict__ w2, const float* __restrict__ b2,
    const float* __restrict__ w3, const float* __restrict__ b3,
    const float* __restrict__ w4, const float* __restrict__ b4,
    float* __restrict__ out) {
  __shared__ float sg[64], s1[64], s2[32], s3[32];
  int g = blockIdx.x, t = threadIdx.x;
  int beg = gstart[g], end = gstart[g + 1];
  float acc = 0.0f;
#pragma unroll 4
  for (int n = beg; n < end; ++n) acc += bfs(H[(size_t)n * 64 + t]);
  float cnt = fmaxf((float)(end - beg), 1.0f);
  sg[t] = acc / cnt;
  __syncthreads();
  acc = b1[t];
  for (int k = 0; k < 64; ++k) acc += sg[k] * w1[k * 64 + t];
  s1[t] = fmaxf(acc, 0.0f);
  __syncthreads();
  if (t < 32) {
    acc = b2[t];
    for (int k = 0; k < 64; ++k) acc += s1[k] * w2[k * 32 + t];
    s2[t] = fmaxf(acc, 0.0f);
  }
  __syncthreads();
  if (t < 32) {
    acc = b3[t];
    for (int k = 0; k < 32; ++k) acc += s2[k] * w3[k * 32 + t];
    s3[t] = fmaxf(acc, 0.0f);
  }
  __syncthreads();
  if (t == 0) {
    acc = b4[0];
    for (int k = 0; k < 32; ++k) acc += s3[k] * w4[k];
    out[g] = acc;
  }
}

// ---------------------------------------------------------------- launch ----
extern "C" void kernel_launch(void* const* d_in, const int* in_sizes, int n_in,
                              void* d_out, int out_size, void* d_ws,
                              size_t ws_size, hipStream_t stream) {
  const float* x     = (const float*)d_in[0];
  const int*   ei    = (const int*)d_in[1];
  const int*   batch = (const int*)d_in[2];
  const int* src = ei;
  const int* dst = ei + NE;

  const float* c1_wl = (const float*)d_in[3];
  const float* c1_bl = (const float*)d_in[4];
  const float* c1_wr = (const float*)d_in[5];
  const float* c2_wl = (const float*)d_in[6];
  const float* c2_bl = (const float*)d_in[7];
  const float* c2_wr = (const float*)d_in[8];
  const float* c3_wl = (const float*)d_in[9];
  const float* c3_bl = (const float*)d_in[10];
  const float* c3_wr = (const float*)d_in[11];
  const float* c4_wl = (const float*)d_in[12];
  const float* c4_bl = (const float*)d_in[13];
  const float* c4_wr = (const float*)d_in[14];
  const float* l1w = (const float*)d_in[15];
  const float* l1b = (const float*)d_in[16];
  const float* l2w = (const float*)d_in[17];
  const float* l2b = (const float*)d_in[18];
  const float* l3w = (const float*)d_in[19];
  const float* l3b = (const float*)d_in[20];
  const float* l4w = (const float*)d_in[21];
  const float* l4b = (const float*)d_in[22];

  // ---- workspace carve-up
  char* wsb = (char*)d_ws;
  float* inv = (float*)wsb;                                   // NN fp32
  unsigned short* xb  = (unsigned short*)(wsb + (size_t)NN * 4);
  unsigned short* B1  = xb + (size_t)NN * 64;    // h2 / h4
  unsigned short* B2  = B1 + (size_t)NN * 64;    // h1 (NN x 128)
  unsigned short* B3  = B2 + (size_t)NN * 128;   // U / h3
  unsigned short* B4  = B3 + (size_t)NN * 64;    // V
  unsigned short* pL1  = B4 + (size_t)NN * 64;   // 128x128 pack
  unsigned short* pL2a = pL1 + 128 * 128;
  unsigned short* pL2b = pL2a + 128 * 64;
  unsigned short* pL3  = pL2b + 128 * 64;
  unsigned short* pL4  = pL3 + 128 * 64;
  int* cnt    = (int*)(pL4 + 128 * 64);          // NN
  int* off    = cnt + NN;                        // NN+1
  int* bsum   = off + NN + 1;                    // 512
  int* gstart = bsum + 512;                      // NG+1
  int* csr    = gstart + NG + 1 + 2;             // NE
  int* rank   = csr + NE;                        // NE

  const int gE  = (NE + 255) / 256;   // 6250
  const int gN8 = NN * 8 / 256;       // 3125  (gather)
  const int gM  = (NN + 63) / 64;     // 1563  (gemm/fgemm x)
  const int gN  = NBLK_SCAN;          // 391

  hipMemsetAsync(cnt, 0, (size_t)NN * 4, stream);

  // ---- setup + CSR
  k_setup<<<GB_SETUP, 256, 0, stream>>>(dst, cnt, rank, x, xb, batch, gstart,
                                        c1_wl, c1_wr, c2_wl, c2_wr,
                                        c3_wl, c3_wr, c4_wl, c4_wr,
                                        pL1, pL2a, pL2b, pL3, pL4);
  k_scan1<<<gN, 256, 0, stream>>>(cnt, off, bsum);
  k_scan23<<<gN, 256, 0, stream>>>(off, bsum, cnt, inv);
  k_fill<<<dim3(gE, NPART), 256, 0, stream>>>(src, dst, off, rank, csr);

  // ---- layer 1 (fused): B2(h1) = relu([agg(x)|x] @ pL1 + c1_bl)
  k_fgemm<8><<<gM, 256, 0, stream>>>(xb, csr, off, inv, pL1, c1_bl, B2, 128);

  // ---- layer 2: B3 = h1@wl, B4 = h1@wr; B1(h2) = relu(agg(B3) + b + B4)
  k_gemm<<<dim3(gM, 2), 256, 0, stream>>>(B2, pL2a, pL2b, B4, B3, NN);
  k_gather<<<gN8, 256, 0, stream>>>(B3, csr, off, inv, c2_bl, B4, B1);

  // ---- layer 3 (fused): B3(h3) = relu([agg(h2)|h2] @ pL3 + c3_bl)
  k_fgemm<4><<<gM, 256, 0, stream>>>(B1, csr, off, inv, pL3, c3_bl, B3, 64);

  // ---- layer 4 (fused): B1(h4) = relu([agg(h3)|h3] @ pL4 + c4_bl)
  k_fgemm<4><<<gM, 256, 0, stream>>>(B3, csr, off, inv, pL4, c4_bl, B1, 64);

  // ---- fused pool + MLP
  k_poolmlp<<<NG, 64, 0, stream>>>(B1, gstart, l1w, l1b, l2w, l2b,
                                   l3w, l3b, l4w, l4b, (float*)d_out);
}

// Round 9
// 406.679 us; speedup vs baseline: 2.2776x; 1.0098x over previous
//
#include <hip/hip_runtime.h>

#define NN 100000
#define NE 1600000
#define NG 1024
#define NBLK_SCAN ((NN + 255) / 256)  // 391
#define NPART 2

// padded counters: one int per 64B line (kills same-line atomic RMW chains)
#define CPAD 16

// merged-setup grid layout
#define GB_COUNT 6250   // NE/256
#define GB_CVT   3125   // NN*64/8/256
#define GB_BND   5
#define GB_PREP  320    // 5 matrices x 64 blocks
#define GB_SETUP (GB_COUNT + GB_CVT + GB_BND + GB_PREP)

typedef __attribute__((ext_vector_type(8))) short bf16x8;
typedef __attribute__((ext_vector_type(4))) float f32x4;

__device__ __forceinline__ unsigned f2bf1(float f) {
  union { float f; unsigned u; } v; v.f = f;
  return (v.u + 0x7fffu + ((v.u >> 16) & 1u)) >> 16;  // RNE
}
__device__ __forceinline__ unsigned packbf2(float a, float b) {
  return f2bf1(a) | (f2bf1(b) << 16);
}
__device__ __forceinline__ float bflo(unsigned u) {
  union { unsigned u; float f; } v; v.u = u << 16; return v.f;
}
__device__ __forceinline__ float bfhi(unsigned u) {
  union { unsigned u; float f; } v; v.u = u & 0xffff0000u; return v.f;
}
__device__ __forceinline__ float bfs(unsigned short s) {
  union { unsigned u; float f; } v; v.u = ((unsigned)s) << 16; return v.f;
}

// ---------------------------------------------------------- merged setup ----
__global__ __launch_bounds__(256) void k_setup(
    const int* __restrict__ dst, int* __restrict__ cnt, int* __restrict__ rank,
    const float* __restrict__ X, unsigned short* __restrict__ Xb,
    const int* __restrict__ batch, int* __restrict__ gstart,
    const float* __restrict__ c1wl, const float* __restrict__ c1wr,
    const float* __restrict__ c2wl, const float* __restrict__ c2wr,
    const float* __restrict__ c3wl, const float* __restrict__ c3wr,
    const float* __restrict__ c4wl, const float* __restrict__ c4wr,
    unsigned short* __restrict__ pL1, unsigned short* __restrict__ pL2a,
    unsigned short* __restrict__ pL2b, unsigned short* __restrict__ pL3,
    unsigned short* __restrict__ pL4) {
  int b = blockIdx.x, tid = threadIdx.x;
  if (b < GB_COUNT) {
    int e = b * 256 + tid;
    rank[e] = atomicAdd(&cnt[(size_t)dst[e] * CPAD], 1);
    return;
  }
  b -= GB_COUNT;
  if (b < GB_CVT) {
    int i = b * 256 + tid;
    const float4* p = (const float4*)X + (size_t)i * 2;
    float4 a = p[0], c = p[1];
    uint4 o;
    o.x = packbf2(a.x, a.y); o.y = packbf2(a.z, a.w);
    o.z = packbf2(c.x, c.y); o.w = packbf2(c.z, c.w);
    ((uint4*)Xb)[i] = o;
    return;
  }
  b -= GB_CVT;
  if (b < GB_BND) {
    int g = b * 256 + tid;
    if (g > NG) return;
    int lo = 0, hi = NN;
    while (lo < hi) {
      int mid = (lo + hi) >> 1;
      if (batch[mid] < g) lo = mid + 1; else hi = mid;
    }
    gstart[g] = lo;
    return;
  }
  b -= GB_BND;
  {
    int yb = b >> 6, xb = b & 63;
    const float *WL, *WR; unsigned short* dstp; int N;
    if (yb == 0)      { WL = c1wl; WR = c1wr;           dstp = pL1;  N = 128; }
    else if (yb == 1) { WL = c2wl; WR = c2wl + 64 * 64; dstp = pL2a; N = 64; }
    else if (yb == 2) { WL = c2wr; WR = c2wr + 64 * 64; dstp = pL2b; N = 64; }
    else if (yb == 3) { WL = c3wl; WR = c3wr;           dstp = pL3;  N = 64; }
    else              { WL = c4wl; WR = c4wr;           dstp = pL4;  N = 64; }
    int e = xb * 256 + tid;
    if (e >= 128 * N) return;
    int k = e / N, n = e - k * N;
    float w = (k < 64) ? WL[k * N + n] : WR[(k - 64) * N + n];
    int t = k >> 5, kq = (k >> 3) & 3, j = k & 7;
    int n0 = n >> 4, nl = n & 15;
    dstp[((((n0 * 4 + t) * 64) + (kq * 16 + nl)) << 3) + j] =
        (unsigned short)f2bf1(w);
  }
}

// ------------------------------------------------------------------ scans ---
__global__ __launch_bounds__(256) void k_scan1(const int* __restrict__ cnt,
                                               int* __restrict__ off,
                                               int* __restrict__ bsum) {
  __shared__ int s[256];
  int tid = threadIdx.x;
  int i = blockIdx.x * 256 + tid;
  int v = (i < NN) ? cnt[(size_t)i * CPAD] : 0;
  s[tid] = v;
  __syncthreads();
  for (int d = 1; d < 256; d <<= 1) {
    int t = (tid >= d) ? s[tid - d] : 0;
    __syncthreads();
    s[tid] += t;
    __syncthreads();
  }
  if (i < NN) off[i] = s[tid] - v;
  if (tid == 255) bsum[blockIdx.x] = s[255];
}

// scan stages 2+3 merged + invdeg fused
__global__ __launch_bounds__(256) void k_scan23(int* __restrict__ off,
                                                const int* __restrict__ bsum,
                                                const int* __restrict__ cnt,
                                                float* __restrict__ inv) {
  __shared__ int red[256];
  int b = blockIdx.x, tid = threadIdx.x;
  int s = 0;
  for (int j = tid; j < b; j += 256) s += bsum[j];
  red[tid] = s;
  __syncthreads();
  for (int d = 128; d > 0; d >>= 1) {
    if (tid < d) red[tid] += red[tid + d];
    __syncthreads();
  }
  int base = red[0];
  int i = b * 256 + tid;
  if (i < NN) {
    off[i] = off[i] + base;
    inv[i] = 1.0f / fmaxf((float)cnt[(size_t)i * CPAD], 1.0f);
  }
  if (i == 0) off[NN] = NE;
}

__global__ __launch_bounds__(256) void k_fill(const int* __restrict__ src,
                                              const int* __restrict__ dst,
                                              const int* __restrict__ off,
                                              const int* __restrict__ rank,
                                              int* __restrict__ csr) {
  int e = blockIdx.x * 256 + threadIdx.x;
  int lo = (int)blockIdx.y * (NN / NPART);
  int hi = lo + (NN / NPART);
  if (e < NE) {
    int d = dst[e];
    if (d >= lo && d < hi) csr[off[d] + rank[e]] = src[e];
  }
}

// ---------------------------- gather (layer-2 epilogue only: relu(agg+b+Z)) -
__global__ __launch_bounds__(256) void k_gather(
    const unsigned short* __restrict__ F, const int* __restrict__ csr,
    const int* __restrict__ off, const float* __restrict__ inv,
    const float* __restrict__ bias, const unsigned short* __restrict__ Z,
    unsigned short* __restrict__ out) {
  int idx = blockIdx.x * 256 + threadIdx.x;  // grid = NN*8 threads
  int n = idx >> 3, q = idx & 7;
  int beg = off[n], end = off[n + 1];
  float aA[8], aB[8];
#pragma unroll
  for (int c = 0; c < 8; ++c) { aA[c] = 0.f; aB[c] = 0.f; }
  int e = beg;
  for (; e + 4 <= end; e += 4) {
    uint4 v[4];
#pragma unroll
    for (int j = 0; j < 4; ++j)
      v[j] = ((const uint4*)(F + (size_t)csr[e + j] * 64))[q];
#pragma unroll
    for (int j = 0; j < 4; j += 2) {
      aA[0] += bflo(v[j].x); aB[0] += bflo(v[j + 1].x);
      aA[1] += bfhi(v[j].x); aB[1] += bfhi(v[j + 1].x);
      aA[2] += bflo(v[j].y); aB[2] += bflo(v[j + 1].y);
      aA[3] += bfhi(v[j].y); aB[3] += bfhi(v[j + 1].y);
      aA[4] += bflo(v[j].z); aB[4] += bflo(v[j + 1].z);
      aA[5] += bfhi(v[j].z); aB[5] += bfhi(v[j + 1].z);
      aA[6] += bflo(v[j].w); aB[6] += bflo(v[j + 1].w);
      aA[7] += bfhi(v[j].w); aB[7] += bfhi(v[j + 1].w);
    }
  }
  for (; e < end; ++e) {
    uint4 v0 = ((const uint4*)(F + (size_t)csr[e] * 64))[q];
    aA[0] += bflo(v0.x); aA[1] += bfhi(v0.x);
    aA[2] += bflo(v0.y); aA[3] += bfhi(v0.y);
    aA[4] += bflo(v0.z); aA[5] += bfhi(v0.z);
    aA[6] += bflo(v0.w); aA[7] += bfhi(v0.w);
  }
  float a[8];
  float iv = inv[n];
#pragma unroll
  for (int c = 0; c < 8; ++c) a[c] = (aA[c] + aB[c]) * iv;
  {
    uint4 z = ((const uint4*)(Z + (size_t)n * 64))[q];
    const float4* bp = (const float4*)(bias + q * 8);
    float4 b0 = bp[0], b1 = bp[1];
    a[0] = fmaxf(a[0] + b0.x + bflo(z.x), 0.f);
    a[1] = fmaxf(a[1] + b0.y + bfhi(z.x), 0.f);
    a[2] = fmaxf(a[2] + b0.z + bflo(z.y), 0.f);
    a[3] = fmaxf(a[3] + b0.w + bfhi(z.y), 0.f);
    a[4] = fmaxf(a[4] + b1.x + bflo(z.z), 0.f);
    a[5] = fmaxf(a[5] + b1.y + bfhi(z.z), 0.f);
    a[6] = fmaxf(a[6] + b1.z + bflo(z.w), 0.f);
    a[7] = fmaxf(a[7] + b1.w + bfhi(z.w), 0.f);
  }
  uint4 o;
  o.x = packbf2(a[0], a[1]); o.y = packbf2(a[2], a[3]);
  o.z = packbf2(a[4], a[5]); o.w = packbf2(a[6], a[7]);
  ((uint4*)(out + (size_t)n * 64))[q] = o;
}

// ------------------------------------------- fused gather + MFMA GEMM -------
template <int NF>  // 8 (128 cols) or 4 (64 cols)
__global__ __launch_bounds__(256, 4) void k_fgemm(
    const unsigned short* __restrict__ F, const int* __restrict__ csr,
    const int* __restrict__ off, const float* __restrict__ inv,
    const unsigned short* __restrict__ Wp, const float* __restrict__ bias,
    unsigned short* __restrict__ OUT, int outStride) {
  __shared__ __align__(16) char smem[64 * 66 * 4];  // sA 16384B / sC 16896B
  unsigned short* sA = (unsigned short*)smem;
  float* sC = (float*)smem;
  const int tid = threadIdx.x;
  const int m0 = blockIdx.x * 64;

  // ---- phase A: gather-aggregate into A-frag K-half 0 (k8 0..7)
  {
    int m = tid >> 2, qr = tid & 3;  // 4 threads/node, 16 channels each
    int row = m0 + m;
    float a0[16], a1[16];
#pragma unroll
    for (int c = 0; c < 16; ++c) { a0[c] = 0.f; a1[c] = 0.f; }
    if (row < NN) {
      int beg = off[row], end = off[row + 1];
      int e = beg;
      for (; e + 2 <= end; e += 2) {
        int s0 = csr[e], s1 = csr[e + 1];
        const uint4* r0 = (const uint4*)(F + (size_t)s0 * 64) + qr * 2;
        const uint4* r1 = (const uint4*)(F + (size_t)s1 * 64) + qr * 2;
        uint4 p0 = r0[0], p1 = r0[1], q0 = r1[0], q1 = r1[1];
        a0[0] += bflo(p0.x); a0[1] += bfhi(p0.x);
        a0[2] += bflo(p0.y); a0[3] += bfhi(p0.y);
        a0[4] += bflo(p0.z); a0[5] += bfhi(p0.z);
        a0[6] += bflo(p0.w); a0[7] += bfhi(p0.w);
        a0[8] += bflo(p1.x); a0[9] += bfhi(p1.x);
        a0[10] += bflo(p1.y); a0[11] += bfhi(p1.y);
        a0[12] += bflo(p1.z); a0[13] += bfhi(p1.z);
        a0[14] += bflo(p1.w); a0[15] += bfhi(p1.w);
        a1[0] += bflo(q0.x); a1[1] += bfhi(q0.x);
        a1[2] += bflo(q0.y); a1[3] += bfhi(q0.y);
        a1[4] += bflo(q0.z); a1[5] += bfhi(q0.z);
        a1[6] += bflo(q0.w); a1[7] += bfhi(q0.w);
        a1[8] += bflo(q1.x); a1[9] += bfhi(q1.x);
        a1[10] += bflo(q1.y); a1[11] += bfhi(q1.y);
        a1[12] += bflo(q1.z); a1[13] += bfhi(q1.z);
        a1[14] += bflo(q1.w); a1[15] += bfhi(q1.w);
      }
      if (e < end) {
        const uint4* r0 = (const uint4*)(F + (size_t)csr[e] * 64) + qr * 2;
        uint4 p0 = r0[0], p1 = r0[1];
        a0[0] += bflo(p0.x); a0[1] += bfhi(p0.x);
        a0[2] += bflo(p0.y); a0[3] += bfhi(p0.y);
        a0[4] += bflo(p0.z); a0[5] += bfhi(p0.z);
        a0[6] += bflo(p0.w); a0[7] += bfhi(p0.w);
        a0[8] += bflo(p1.x); a0[9] += bfhi(p1.x);
        a0[10] += bflo(p1.y); a0[11] += bfhi(p1.y);
        a0[12] += bflo(p1.z); a0[13] += bfhi(p1.z);
        a0[14] += bflo(p1.w); a0[15] += bfhi(p1.w);
      }
      float iv = inv[row];
#pragma unroll
      for (int c = 0; c < 16; ++c) a0[c] = (a0[c] + a1[c]) * iv;
    } else {
#pragma unroll
      for (int c = 0; c < 16; ++c) a0[c] = 0.f;
    }
    int wv = m >> 4, mr = m & 15;
#pragma unroll
    for (int h = 0; h < 2; ++h) {
      int k8 = qr * 2 + h;             // 0..7
      int t = k8 >> 2, kq = k8 & 3;
      uint4 o;
      o.x = packbf2(a0[h * 8 + 0], a0[h * 8 + 1]);
      o.y = packbf2(a0[h * 8 + 2], a0[h * 8 + 3]);
      o.z = packbf2(a0[h * 8 + 4], a0[h * 8 + 5]);
      o.w = packbf2(a0[h * 8 + 6], a0[h * 8 + 7]);
      ((uint4*)sA)[(wv * 4 + t) * 64 + kq * 16 + mr] = o;
    }
  }
  // ---- phase B: stage own rows as K-half 1 (k8 8..15)
#pragma unroll
  for (int l = 0; l < 2; ++l) {
    int c = tid + l * 256;  // 512 chunks: m(64) x j(8)
    int m = c >> 3, j = c & 7;
    int row = m0 + m;
    uint4 v = make_uint4(0, 0, 0, 0);
    if (row < NN) v = ((const uint4*)(F + (size_t)row * 64))[j];
    int k8 = 8 + j, t = k8 >> 2, kq = k8 & 3;
    int wv = m >> 4, mr = m & 15;
    ((uint4*)sA)[(wv * 4 + t) * 64 + kq * 16 + mr] = v;
  }
  __syncthreads();

  const int w = tid >> 6, L = tid & 63;
  const bf16x8* Af = (const bf16x8*)sA;
  const bf16x8* Bf = (const bf16x8*)Wp;
  f32x4 acc[NF];
#pragma unroll
  for (int i = 0; i < NF; ++i)
#pragma unroll
    for (int j = 0; j < 4; ++j) acc[i][j] = 0.f;
#pragma unroll
  for (int t = 0; t < 4; ++t) {
    bf16x8 afr = Af[(w * 4 + t) * 64 + L];
#pragma unroll
    for (int n0 = 0; n0 < NF; ++n0) {
      bf16x8 bfr = Bf[(n0 * 4 + t) * 64 + L];
      acc[n0] = __builtin_amdgcn_mfma_f32_16x16x32_bf16(afr, bfr, acc[n0], 0, 0, 0);
    }
  }

  // ---- epilogue in rounds of 64 cols (sC reuses sA space)
  int rg = L >> 4, cl = L & 15;
#pragma unroll
  for (int half = 0; half < NF / 4; ++half) {
    __syncthreads();
#pragma unroll
    for (int n0 = 0; n0 < 4; ++n0)
#pragma unroll
      for (int r = 0; r < 4; ++r)
        sC[(w * 16 + rg * 4 + r) * 66 + n0 * 16 + cl] = acc[half * 4 + n0][r];
    __syncthreads();
#pragma unroll
    for (int it = 0; it < 2; ++it) {
      int c = tid + it * 256;
      int m = c >> 3, c8 = c & 7;
      int row = m0 + m;
      if (row < NN) {
        float v[8];
#pragma unroll
        for (int j = 0; j < 8; ++j)
          v[j] = fmaxf(sC[m * 66 + c8 * 8 + j] + bias[half * 64 + c8 * 8 + j], 0.f);
        uint4 o;
        o.x = packbf2(v[0], v[1]); o.y = packbf2(v[2], v[3]);
        o.z = packbf2(v[4], v[5]); o.w = packbf2(v[6], v[7]);
        ((uint4*)(OUT + (size_t)row * outStride + half * 64))[c8] = o;
      }
    }
  }
}

// ------------------------------------------------------------ MFMA GEMM -----
// (layer 2 only: h1 @ wl -> OUT, h1 @ wr -> OUT2)
__global__ __launch_bounds__(256) void k_gemm(
    const unsigned short* __restrict__ S0,
    const unsigned short* __restrict__ Wp,
    const unsigned short* __restrict__ Wp2, unsigned short* __restrict__ OUT2,
    unsigned short* __restrict__ OUT, int M) {
  __shared__ __align__(16) char smem[64 * 66 * 4];
  unsigned short* sA = (unsigned short*)smem;
  float* sC = (float*)smem;
  const int tid = threadIdx.x;
  if (blockIdx.y == 1) { Wp = Wp2; OUT = OUT2; }
  const int m0 = blockIdx.x * 64;

#pragma unroll
  for (int l = 0; l < 4; ++l) {
    int c = tid + l * 256;
    int m = c >> 4, k8 = c & 15;
    int row = m0 + m;
    uint4 v = make_uint4(0, 0, 0, 0);
    if (row < M) v = ((const uint4*)(S0 + (size_t)row * 128))[k8];
    int wv = m >> 4, mr = m & 15, t = k8 >> 2, kq = k8 & 3;
    ((uint4*)sA)[(wv * 4 + t) * 64 + (kq * 16 + mr)] = v;
  }
  __syncthreads();

  const int w = tid >> 6, L = tid & 63;
  f32x4 acc[4];
#pragma unroll
  for (int i = 0; i < 4; ++i)
#pragma unroll
    for (int j = 0; j < 4; ++j) acc[i][j] = 0.f;

  const bf16x8* Af = (const bf16x8*)sA;
  const bf16x8* Bf = (const bf16x8*)Wp;
#pragma unroll
  for (int t = 0; t < 4; ++t) {
    bf16x8 afr = Af[(w * 4 + t) * 64 + L];
#pragma unroll
    for (int n0 = 0; n0 < 4; ++n0) {
      bf16x8 bfr = Bf[(n0 * 4 + t) * 64 + L];
      acc[n0] = __builtin_amdgcn_mfma_f32_16x16x32_bf16(afr, bfr, acc[n0], 0, 0, 0);
    }
  }
  __syncthreads();
  {
    int rg = L >> 4, cl = L & 15;
#pragma unroll
    for (int n0 = 0; n0 < 4; ++n0)
#pragma unroll
      for (int r = 0; r < 4; ++r)
        sC[(w * 16 + rg * 4 + r) * 66 + n0 * 16 + cl] = acc[n0][r];
  }
  __syncthreads();
#pragma unroll
  for (int it = 0; it < 2; ++it) {
    int c = tid + it * 256;
    int m = c >> 3, c8 = c & 7;
    int row = m0 + m;
    if (row < M) {
      float v[8];
#pragma unroll
      for (int j = 0; j < 8; ++j) v[j] = sC[m * 66 + c8 * 8 + j];
      uint4 o;
      o.x = packbf2(v[0], v[1]); o.y = packbf2(v[2], v[3]);
      o.z = packbf2(v[4], v[5]); o.w = packbf2(v[6], v[7]);
      ((uint4*)(OUT + (size_t)row * 64))[c8] = o;
    }
  }
}

// ----------------------------------------------- fused mean-pool + MLP ------
__global__ __launch_bounds__(64) void k_poolmlp(
    const unsigned short* __restrict__ H, const int* __restrict__ gstart,
    const float* __restrict__ w1, const float* __restrict__ b1,
    const float* __restrict__ w2, const float* __restrict__ b2,
    const float* __restrict__ w3, const float* __restrict__ b3,
    const float* __restrict__ w4, const float* __restrict__ b4,
    float* __restrict__ out) {
  __shared__ float sg[64], s1[64], s2[32], s3[32];
  int g = blockIdx.x, t = threadIdx.x;
  int beg = gstart[g], end = gstart[g + 1];
  float acc = 0.0f;
#pragma unroll 4
  for (int n = beg; n < end; ++n) acc += bfs(H[(size_t)n * 64 + t]);
  float cnt = fmaxf((float)(end - beg), 1.0f);
  sg[t] = acc / cnt;
  __syncthreads();
  acc = b1[t];
  for (int k = 0; k < 64; ++k) acc += sg[k] * w1[k * 64 + t];
  s1[t] = fmaxf(acc, 0.0f);
  __syncthreads();
  if (t < 32) {
    acc = b2[t];
    for (int k = 0; k < 64; ++k) acc += s1[k] * w2[k * 32 + t];
    s2[t] = fmaxf(acc, 0.0f);
  }
  __syncthreads();
  if (t < 32) {
    acc = b3[t];
    for (int k = 0; k < 32; ++k) acc += s2[k] * w3[k * 32 + t];
    s3[t] = fmaxf(acc, 0.0f);
  }
  __syncthreads();
  if (t == 0) {
    acc = b4[0];
    for (int k = 0; k < 32; ++k) acc += s3[k] * w4[k];
    out[g] = acc;
  }
}

// ---------------------------------------------------------------- launch ----
extern "C" void kernel_launch(void* const* d_in, const int* in_sizes, int n_in,
                              void* d_out, int out_size, void* d_ws,
                              size_t ws_size, hipStream_t stream) {
  const float* x     = (const float*)d_in[0];
  const int*   ei    = (const int*)d_in[1];
  const int*   batch = (const int*)d_in[2];
  const int* src = ei;
  const int* dst = ei + NE;

  const float* c1_wl = (const float*)d_in[3];
  const float* c1_bl = (const float*)d_in[4];
  const float* c1_wr = (const float*)d_in[5];
  const float* c2_wl = (const float*)d_in[6];
  const float* c2_bl = (const float*)d_in[7];
  const float* c2_wr = (const float*)d_in[8];
  const float* c3_wl = (const float*)d_in[9];
  const float* c3_bl = (const float*)d_in[10];
  const float* c3_wr = (const float*)d_in[11];
  const float* c4_wl = (const float*)d_in[12];
  const float* c4_bl = (const float*)d_in[13];
  const float* c4_wr = (const float*)d_in[14];
  const float* l1w = (const float*)d_in[15];
  const float* l1b = (const float*)d_in[16];
  const float* l2w = (const float*)d_in[17];
  const float* l2b = (const float*)d_in[18];
  const float* l3w = (const float*)d_in[19];
  const float* l3b = (const float*)d_in[20];
  const float* l4w = (const float*)d_in[21];
  const float* l4b = (const float*)d_in[22];

  // ---- workspace carve-up
  char* wsb = (char*)d_ws;
  float* inv = (float*)wsb;                                   // NN fp32
  unsigned short* xb  = (unsigned short*)(wsb + (size_t)NN * 4);
  unsigned short* B1  = xb + (size_t)NN * 64;    // h2 / h4
  unsigned short* B2  = B1 + (size_t)NN * 64;    // h1 (NN x 128)
  unsigned short* B3  = B2 + (size_t)NN * 128;   // U / h3
  unsigned short* B4  = B3 + (size_t)NN * 64;    // V
  unsigned short* pL1  = B4 + (size_t)NN * 64;   // 128x128 pack
  unsigned short* pL2a = pL1 + 128 * 128;
  unsigned short* pL2b = pL2a + 128 * 64;
  unsigned short* pL3  = pL2b + 128 * 64;
  unsigned short* pL4  = pL3 + 128 * 64;
  int* cnt    = (int*)(pL4 + 128 * 64);          // NN*CPAD (padded, 6.4MB)
  int* off    = cnt + (size_t)NN * CPAD;         // NN+1
  int* bsum   = off + NN + 1;                    // 512
  int* gstart = bsum + 512;                      // NG+1
  int* csr    = gstart + NG + 1 + 2;             // NE
  int* rank   = csr + NE;                        // NE

  const int gE  = (NE + 255) / 256;   // 6250
  const int gN8 = NN * 8 / 256;       // 3125  (gather)
  const int gM  = (NN + 63) / 64;     // 1563  (gemm/fgemm x)
  const int gN  = NBLK_SCAN;          // 391

  hipMemsetAsync(cnt, 0, (size_t)NN * CPAD * 4, stream);

  // ---- setup + CSR
  k_setup<<<GB_SETUP, 256, 0, stream>>>(dst, cnt, rank, x, xb, batch, gstart,
                                        c1_wl, c1_wr, c2_wl, c2_wr,
                                        c3_wl, c3_wr, c4_wl, c4_wr,
                                        pL1, pL2a, pL2b, pL3, pL4);
  k_scan1<<<gN, 256, 0, stream>>>(cnt, off, bsum);
  k_scan23<<<gN, 256, 0, stream>>>(off, bsum, cnt, inv);
  k_fill<<<dim3(gE, NPART), 256, 0, stream>>>(src, dst, off, rank, csr);

  // ---- layer 1 (fused): B2(h1) = relu([agg(x)|x] @ pL1 + c1_bl)
  k_fgemm<8><<<gM, 256, 0, stream>>>(xb, csr, off, inv, pL1, c1_bl, B2, 128);

  // ---- layer 2: B3 = h1@wl, B4 = h1@wr; B1(h2) = relu(agg(B3) + b + B4)
  k_gemm<<<dim3(gM, 2), 256, 0, stream>>>(B2, pL2a, pL2b, B4, B3, NN);
  k_gather<<<gN8, 256, 0, stream>>>(B3, csr, off, inv, c2_bl, B4, B1);

  // ---- layer 3 (fused): B3(h3) = relu([agg(h2)|h2] @ pL3 + c3_bl)
  k_fgemm<4><<<gM, 256, 0, stream>>>(B1, csr, off, inv, pL3, c3_bl, B3, 64);

  // ---- layer 4 (fused): B1(h4) = relu([agg(h3)|h3] @ pL4 + c4_bl)
  k_fgemm<4><<<gM, 256, 0, stream>>>(B3, csr, off, inv, pL4, c4_bl, B1, 64);

  // ---- fused pool + MLP
  k_poolmlp<<<NG, 64, 0, stream>>>(B1, gstart, l1w, l1b, l2w, l2b,
                                   l3w, l3b, l4w, l4b, (float*)d_out);
}

// Round 10
// 401.997 us; speedup vs baseline: 2.3042x; 1.0116x over previous
//
#include <hip/hip_runtime.h>

#define NN 100000
#define NE 1600000
#define NG 1024
#define NBLK_SCAN ((NN + 255) / 256)  // 391
#define NPART 2
#define CPAD 4   // counter stride (ints). R8/R9: atomic-throughput-bound either way

// merged-setup grid: even blocks = count (atomic-stalled, idle pipes),
// odd blocks = compute (Z-gemm/cvt/bounds/prep) -> co-scheduled per CU.
#define GB_COUNT 6250   // NE/256
#define GB_Z     1563   // ceil(NN/64) Z-gemm blocks
#define GB_CVT   3125   // NN*64/8/256
#define GB_BND   5
#define GB_PREP  320    // 5 matrices x 64 blocks
#define GB_SETUP (2 * GB_COUNT)  // 12500; odd side holds 5013 work blocks

typedef __attribute__((ext_vector_type(8))) short bf16x8;
typedef __attribute__((ext_vector_type(4))) float f32x4;

__device__ __forceinline__ unsigned f2bf1(float f) {
  union { float f; unsigned u; } v; v.f = f;
  return (v.u + 0x7fffu + ((v.u >> 16) & 1u)) >> 16;  // RNE
}
__device__ __forceinline__ unsigned packbf2(float a, float b) {
  return f2bf1(a) | (f2bf1(b) << 16);
}
__device__ __forceinline__ float bflo(unsigned u) {
  union { unsigned u; float f; } v; v.u = u << 16; return v.f;
}
__device__ __forceinline__ float bfhi(unsigned u) {
  union { unsigned u; float f; } v; v.u = u & 0xffff0000u; return v.f;
}
__device__ __forceinline__ float bfs(unsigned short s) {
  union { unsigned u; float f; } v; v.u = ((unsigned)s) << 16; return v.f;
}

// ---------------------- pre-pack c1_wr (K=64,N=128) B-frags for the Z-gemm --
__global__ __launch_bounds__(256) void k_prepz(const float* __restrict__ c1wr,
                                               unsigned short* __restrict__ pLZ) {
  int e = blockIdx.x * 256 + threadIdx.x;  // 64*128 = 8192
  if (e >= 64 * 128) return;
  int k = e >> 7, n = e & 127;
  int t = k >> 5, kq = (k >> 3) & 3, j = k & 7;
  int n0 = n >> 4, nl = n & 15;
  pLZ[((((n0 * 2 + t) * 64) + (kq * 16 + nl)) << 3) + j] =
      (unsigned short)f2bf1(c1wr[k * 128 + n]);
}

// ---------------------------------------------------------- merged setup ----
__global__ __launch_bounds__(256) void k_setup(
    const int* __restrict__ dst, int* __restrict__ cnt, int* __restrict__ rank,
    const float* __restrict__ X, unsigned short* __restrict__ Xb,
    const int* __restrict__ batch, int* __restrict__ gstart,
    const unsigned short* __restrict__ pLZ, const float* __restrict__ c1bl,
    unsigned short* __restrict__ ZZ,
    const float* __restrict__ c1wl, const float* __restrict__ c1wr,
    const float* __restrict__ c2wl, const float* __restrict__ c2wr,
    const float* __restrict__ c3wl, const float* __restrict__ c3wr,
    const float* __restrict__ c4wl, const float* __restrict__ c4wr,
    unsigned short* __restrict__ pL1, unsigned short* __restrict__ pL2a,
    unsigned short* __restrict__ pL2b, unsigned short* __restrict__ pL3,
    unsigned short* __restrict__ pL4) {
  __shared__ __align__(16) char smem[64 * 66 * 4];  // Z-gemm sA/sC
  int b = blockIdx.x, tid = threadIdx.x;

  if ((b & 1) == 0) {  // ---- count (atomic-bound; pipes idle)
    int e = (b >> 1) * 256 + tid;
    rank[e] = atomicAdd(&cnt[(size_t)dst[e] * CPAD], 1);
    return;
  }
  int ob = b >> 1;

  if (ob < GB_Z) {  // ---- Z-gemm: ZZ = x @ c1_wr + c1_bl  (bf16, no relu)
    unsigned short* sA = (unsigned short*)smem;
    float* sC = (float*)smem;
    const int m0 = ob * 64;
    // stage A (64 rows x 64 k, fp32 -> bf16 A-frags, K=64 layout)
#pragma unroll
    for (int l = 0; l < 2; ++l) {
      int c = tid + l * 256;  // 512 chunks
      int m = c >> 3, k8 = c & 7;
      int row = m0 + m;
      uint4 o = make_uint4(0, 0, 0, 0);
      if (row < NN) {
        const float4* xp = (const float4*)(X + (size_t)row * 64 + k8 * 8);
        float4 p0 = xp[0], p1 = xp[1];
        o.x = packbf2(p0.x, p0.y); o.y = packbf2(p0.z, p0.w);
        o.z = packbf2(p1.x, p1.y); o.w = packbf2(p1.z, p1.w);
      }
      int wv = m >> 4, mr = m & 15, t = k8 >> 2, kq = k8 & 3;
      ((uint4*)sA)[(wv * 2 + t) * 64 + kq * 16 + mr] = o;
    }
    __syncthreads();
    const int w = tid >> 6, L = tid & 63;
    const bf16x8* Af = (const bf16x8*)sA;
    const bf16x8* Bf = (const bf16x8*)pLZ;
    f32x4 acc[8];
#pragma unroll
    for (int i = 0; i < 8; ++i)
#pragma unroll
      for (int j = 0; j < 4; ++j) acc[i][j] = 0.f;
#pragma unroll
    for (int t = 0; t < 2; ++t) {
      bf16x8 afr = Af[(w * 2 + t) * 64 + L];
#pragma unroll
      for (int n0 = 0; n0 < 8; ++n0) {
        bf16x8 bfr = Bf[(n0 * 2 + t) * 64 + L];
        acc[n0] = __builtin_amdgcn_mfma_f32_16x16x32_bf16(afr, bfr, acc[n0], 0, 0, 0);
      }
    }
    int rg = L >> 4, cl = L & 15;
#pragma unroll
    for (int half = 0; half < 2; ++half) {
      __syncthreads();
#pragma unroll
      for (int n0 = 0; n0 < 4; ++n0)
#pragma unroll
        for (int r = 0; r < 4; ++r)
          sC[(w * 16 + rg * 4 + r) * 66 + n0 * 16 + cl] = acc[half * 4 + n0][r];
      __syncthreads();
#pragma unroll
      for (int it = 0; it < 2; ++it) {
        int c = tid + it * 256;
        int m = c >> 3, c8 = c & 7;
        int row = m0 + m;
        if (row < NN) {
          float v[8];
#pragma unroll
          for (int j = 0; j < 8; ++j)
            v[j] = sC[m * 66 + c8 * 8 + j] + c1bl[half * 64 + c8 * 8 + j];
          uint4 o;
          o.x = packbf2(v[0], v[1]); o.y = packbf2(v[2], v[3]);
          o.z = packbf2(v[4], v[5]); o.w = packbf2(v[6], v[7]);
          ((uint4*)(ZZ + (size_t)row * 128 + half * 64))[c8] = o;
        }
      }
    }
    return;
  }
  ob -= GB_Z;
  if (ob < GB_CVT) {  // ---- x fp32 -> bf16
    int i = ob * 256 + tid;
    const float4* p = (const float4*)X + (size_t)i * 2;
    float4 a = p[0], c = p[1];
    uint4 o;
    o.x = packbf2(a.x, a.y); o.y = packbf2(a.z, a.w);
    o.z = packbf2(c.x, c.y); o.w = packbf2(c.z, c.w);
    ((uint4*)Xb)[i] = o;
    return;
  }
  ob -= GB_CVT;
  if (ob < GB_BND) {  // ---- graph bounds (sorted batch)
    int g = ob * 256 + tid;
    if (g > NG) return;
    int lo = 0, hi = NN;
    while (lo < hi) {
      int mid = (lo + hi) >> 1;
      if (batch[mid] < g) lo = mid + 1; else hi = mid;
    }
    gstart[g] = lo;
    return;
  }
  ob -= GB_BND;
  if (ob < GB_PREP) {  // ---- pack conv weights (K=128 B-frag layout)
    int yb = ob >> 6, xb = ob & 63;
    const float *WL, *WR; unsigned short* dstp; int N;
    if (yb == 0)      { WL = c1wl; WR = c1wr;           dstp = pL1;  N = 128; }
    else if (yb == 1) { WL = c2wl; WR = c2wl + 64 * 64; dstp = pL2a; N = 64; }
    else if (yb == 2) { WL = c2wr; WR = c2wr + 64 * 64; dstp = pL2b; N = 64; }
    else if (yb == 3) { WL = c3wl; WR = c3wr;           dstp = pL3;  N = 64; }
    else              { WL = c4wl; WR = c4wr;           dstp = pL4;  N = 64; }
    int e = xb * 256 + tid;
    if (e >= 128 * N) return;
    int k = e / N, n = e - k * N;
    float w = (k < 64) ? WL[k * N + n] : WR[(k - 64) * N + n];
    int t = k >> 5, kq = (k >> 3) & 3, j = k & 7;
    int n0 = n >> 4, nl = n & 15;
    dstp[((((n0 * 4 + t) * 64) + (kq * 16 + nl)) << 3) + j] =
        (unsigned short)f2bf1(w);
  }
}

// ------------------------------------------------------------------ scans ---
__global__ __launch_bounds__(256) void k_scan1(const int* __restrict__ cnt,
                                               int* __restrict__ off,
                                               int* __restrict__ bsum) {
  __shared__ int s[256];
  int tid = threadIdx.x;
  int i = blockIdx.x * 256 + tid;
  int v = (i < NN) ? cnt[(size_t)i * CPAD] : 0;
  s[tid] = v;
  __syncthreads();
  for (int d = 1; d < 256; d <<= 1) {
    int t = (tid >= d) ? s[tid - d] : 0;
    __syncthreads();
    s[tid] += t;
    __syncthreads();
  }
  if (i < NN) off[i] = s[tid] - v;
  if (tid == 255) bsum[blockIdx.x] = s[255];
}

__global__ __launch_bounds__(256) void k_scan23(int* __restrict__ off,
                                                const int* __restrict__ bsum,
                                                const int* __restrict__ cnt,
                                                float* __restrict__ inv) {
  __shared__ int red[256];
  int b = blockIdx.x, tid = threadIdx.x;
  int s = 0;
  for (int j = tid; j < b; j += 256) s += bsum[j];
  red[tid] = s;
  __syncthreads();
  for (int d = 128; d > 0; d >>= 1) {
    if (tid < d) red[tid] += red[tid + d];
    __syncthreads();
  }
  int base = red[0];
  int i = b * 256 + tid;
  if (i < NN) {
    off[i] = off[i] + base;
    inv[i] = 1.0f / fmaxf((float)cnt[(size_t)i * CPAD], 1.0f);
  }
  if (i == 0) off[NN] = NE;
}

__global__ __launch_bounds__(256) void k_fill(const int* __restrict__ src,
                                              const int* __restrict__ dst,
                                              const int* __restrict__ off,
                                              const int* __restrict__ rank,
                                              int* __restrict__ csr) {
  int e = blockIdx.x * 256 + threadIdx.x;
  int lo = (int)blockIdx.y * (NN / NPART);
  int hi = lo + (NN / NPART);
  if (e < NE) {
    int d = dst[e];
    if (d >= lo && d < hi) csr[off[d] + rank[e]] = src[e];
  }
}

// ---------------------------- gather (layer-2 epilogue: relu(agg+b+Z)) ------
__global__ __launch_bounds__(256) void k_gather(
    const unsigned short* __restrict__ F, const int* __restrict__ csr,
    const int* __restrict__ off, const float* __restrict__ inv,
    const float* __restrict__ bias, const unsigned short* __restrict__ Z,
    unsigned short* __restrict__ out) {
  int idx = blockIdx.x * 256 + threadIdx.x;  // grid = NN*8 threads
  int n = idx >> 3, q = idx & 7;
  int beg = off[n], end = off[n + 1];
  float aA[8], aB[8];
#pragma unroll
  for (int c = 0; c < 8; ++c) { aA[c] = 0.f; aB[c] = 0.f; }
  int e = beg;
  for (; e + 4 <= end; e += 4) {
    uint4 v[4];
#pragma unroll
    for (int j = 0; j < 4; ++j)
      v[j] = ((const uint4*)(F + (size_t)csr[e + j] * 64))[q];
#pragma unroll
    for (int j = 0; j < 4; j += 2) {
      aA[0] += bflo(v[j].x); aB[0] += bflo(v[j + 1].x);
      aA[1] += bfhi(v[j].x); aB[1] += bfhi(v[j + 1].x);
      aA[2] += bflo(v[j].y); aB[2] += bflo(v[j + 1].y);
      aA[3] += bfhi(v[j].y); aB[3] += bfhi(v[j + 1].y);
      aA[4] += bflo(v[j].z); aB[4] += bflo(v[j + 1].z);
      aA[5] += bfhi(v[j].z); aB[5] += bfhi(v[j + 1].z);
      aA[6] += bflo(v[j].w); aB[6] += bflo(v[j + 1].w);
      aA[7] += bfhi(v[j].w); aB[7] += bfhi(v[j + 1].w);
    }
  }
  for (; e < end; ++e) {
    uint4 v0 = ((const uint4*)(F + (size_t)csr[e] * 64))[q];
    aA[0] += bflo(v0.x); aA[1] += bfhi(v0.x);
    aA[2] += bflo(v0.y); aA[3] += bfhi(v0.y);
    aA[4] += bflo(v0.z); aA[5] += bfhi(v0.z);
    aA[6] += bflo(v0.w); aA[7] += bfhi(v0.w);
  }
  float a[8];
  float iv = inv[n];
#pragma unroll
  for (int c = 0; c < 8; ++c) a[c] = (aA[c] + aB[c]) * iv;
  {
    uint4 z = ((const uint4*)(Z + (size_t)n * 64))[q];
    const float4* bp = (const float4*)(bias + q * 8);
    float4 b0 = bp[0], b1 = bp[1];
    a[0] = fmaxf(a[0] + b0.x + bflo(z.x), 0.f);
    a[1] = fmaxf(a[1] + b0.y + bfhi(z.x), 0.f);
    a[2] = fmaxf(a[2] + b0.z + bflo(z.y), 0.f);
    a[3] = fmaxf(a[3] + b0.w + bfhi(z.y), 0.f);
    a[4] = fmaxf(a[4] + b1.x + bflo(z.z), 0.f);
    a[5] = fmaxf(a[5] + b1.y + bfhi(z.z), 0.f);
    a[6] = fmaxf(a[6] + b1.z + bflo(z.w), 0.f);
    a[7] = fmaxf(a[7] + b1.w + bfhi(z.w), 0.f);
  }
  uint4 o;
  o.x = packbf2(a[0], a[1]); o.y = packbf2(a[2], a[3]);
  o.z = packbf2(a[4], a[5]); o.w = packbf2(a[6], a[7]);
  ((uint4*)(out + (size_t)n * 64))[q] = o;
}

// -------------------- layer-1 fused: h1 = relu(agg(x)@WL + Z)  (K=64) -------
__global__ __launch_bounds__(256, 4) void k_fgemm1(
    const unsigned short* __restrict__ F, const int* __restrict__ csr,
    const int* __restrict__ off, const float* __restrict__ inv,
    const unsigned short* __restrict__ Wp,   // pL1 (K=128 layout; WL = t 0,1)
    const unsigned short* __restrict__ ZZ,   // NN x 128 (x@wr + bias)
    unsigned short* __restrict__ OUT) {
  __shared__ __align__(16) char smem[64 * 66 * 4];
  unsigned short* sA = (unsigned short*)smem;
  float* sC = (float*)smem;
  const int tid = threadIdx.x;
  const int m0 = blockIdx.x * 64;

  // ---- gather-aggregate into K=64 A-frags
  {
    int m = tid >> 2, qr = tid & 3;
    int row = m0 + m;
    float a0[16], a1[16];
#pragma unroll
    for (int c = 0; c < 16; ++c) { a0[c] = 0.f; a1[c] = 0.f; }
    if (row < NN) {
      int beg = off[row], end = off[row + 1];
      int e = beg;
      for (; e + 2 <= end; e += 2) {
        int s0 = csr[e], s1 = csr[e + 1];
        const uint4* r0 = (const uint4*)(F + (size_t)s0 * 64) + qr * 2;
        const uint4* r1 = (const uint4*)(F + (size_t)s1 * 64) + qr * 2;
        uint4 p0 = r0[0], p1 = r0[1], q0 = r1[0], q1 = r1[1];
        a0[0] += bflo(p0.x); a0[1] += bfhi(p0.x);
        a0[2] += bflo(p0.y); a0[3] += bfhi(p0.y);
        a0[4] += bflo(p0.z); a0[5] += bfhi(p0.z);
        a0[6] += bflo(p0.w); a0[7] += bfhi(p0.w);
        a0[8] += bflo(p1.x); a0[9] += bfhi(p1.x);
        a0[10] += bflo(p1.y); a0[11] += bfhi(p1.y);
        a0[12] += bflo(p1.z); a0[13] += bfhi(p1.z);
        a0[14] += bflo(p1.w); a0[15] += bfhi(p1.w);
        a1[0] += bflo(q0.x); a1[1] += bfhi(q0.x);
        a1[2] += bflo(q0.y); a1[3] += bfhi(q0.y);
        a1[4] += bflo(q0.z); a1[5] += bfhi(q0.z);
        a1[6] += bflo(q0.w); a1[7] += bfhi(q0.w);
        a1[8] += bflo(q1.x); a1[9] += bfhi(q1.x);
        a1[10] += bflo(q1.y); a1[11] += bfhi(q1.y);
        a1[12] += bflo(q1.z); a1[13] += bfhi(q1.z);
        a1[14] += bflo(q1.w); a1[15] += bfhi(q1.w);
      }
      if (e < end) {
        const uint4* r0 = (const uint4*)(F + (size_t)csr[e] * 64) + qr * 2;
        uint4 p0 = r0[0], p1 = r0[1];
        a0[0] += bflo(p0.x); a0[1] += bfhi(p0.x);
        a0[2] += bflo(p0.y); a0[3] += bfhi(p0.y);
        a0[4] += bflo(p0.z); a0[5] += bfhi(p0.z);
        a0[6] += bflo(p0.w); a0[7] += bfhi(p0.w);
        a0[8] += bflo(p1.x); a0[9] += bfhi(p1.x);
        a0[10] += bflo(p1.y); a0[11] += bfhi(p1.y);
        a0[12] += bflo(p1.z); a0[13] += bfhi(p1.z);
        a0[14] += bflo(p1.w); a0[15] += bfhi(p1.w);
      }
      float iv = inv[row];
#pragma unroll
      for (int c = 0; c < 16; ++c) a0[c] = (a0[c] + a1[c]) * iv;
    }
    int wv = m >> 4, mr = m & 15;
#pragma unroll
    for (int h = 0; h < 2; ++h) {
      int k8 = qr * 2 + h;  // 0..7, t = k8>>2 in {0,1}
      int t = k8 >> 2, kq = k8 & 3;
      uint4 o;
      o.x = packbf2(a0[h * 8 + 0], a0[h * 8 + 1]);
      o.y = packbf2(a0[h * 8 + 2], a0[h * 8 + 3]);
      o.z = packbf2(a0[h * 8 + 4], a0[h * 8 + 5]);
      o.w = packbf2(a0[h * 8 + 6], a0[h * 8 + 7]);
      ((uint4*)sA)[(wv * 2 + t) * 64 + kq * 16 + mr] = o;
    }
  }
  __syncthreads();

  const int w = tid >> 6, L = tid & 63;
  const bf16x8* Af = (const bf16x8*)sA;
  const bf16x8* Bf = (const bf16x8*)Wp;
  f32x4 acc[8];
#pragma unroll
  for (int i = 0; i < 8; ++i)
#pragma unroll
    for (int j = 0; j < 4; ++j) acc[i][j] = 0.f;
#pragma unroll
  for (int t = 0; t < 2; ++t) {  // WL rows of the K=128 pack
    bf16x8 afr = Af[(w * 2 + t) * 64 + L];
#pragma unroll
    for (int n0 = 0; n0 < 8; ++n0) {
      bf16x8 bfr = Bf[(n0 * 4 + t) * 64 + L];
      acc[n0] = __builtin_amdgcn_mfma_f32_16x16x32_bf16(afr, bfr, acc[n0], 0, 0, 0);
    }
  }

  int rg = L >> 4, cl = L & 15;
#pragma unroll
  for (int half = 0; half < 2; ++half) {
    __syncthreads();
#pragma unroll
    for (int n0 = 0; n0 < 4; ++n0)
#pragma unroll
      for (int r = 0; r < 4; ++r)
        sC[(w * 16 + rg * 4 + r) * 66 + n0 * 16 + cl] = acc[half * 4 + n0][r];
    __syncthreads();
#pragma unroll
    for (int it = 0; it < 2; ++it) {
      int c = tid + it * 256;
      int m = c >> 3, c8 = c & 7;
      int row = m0 + m;
      if (row < NN) {
        uint4 z = ((const uint4*)(ZZ + (size_t)row * 128 + half * 64))[c8];
        float zb[8] = {bflo(z.x), bfhi(z.x), bflo(z.y), bfhi(z.y),
                       bflo(z.z), bfhi(z.z), bflo(z.w), bfhi(z.w)};
        float v[8];
#pragma unroll
        for (int j = 0; j < 8; ++j)
          v[j] = fmaxf(sC[m * 66 + c8 * 8 + j] + zb[j], 0.f);
        uint4 o;
        o.x = packbf2(v[0], v[1]); o.y = packbf2(v[2], v[3]);
        o.z = packbf2(v[4], v[5]); o.w = packbf2(v[6], v[7]);
        ((uint4*)(OUT + (size_t)row * 128 + half * 64))[c8] = o;
      }
    }
  }
}

// ------------------------------------------- fused gather + MFMA GEMM -------
template <int NF>  // 4 (64 cols), K=128: gather half + own half
__global__ __launch_bounds__(256, 4) void k_fgemm(
    const unsigned short* __restrict__ F, const int* __restrict__ csr,
    const int* __restrict__ off, const float* __restrict__ inv,
    const unsigned short* __restrict__ Wp, const float* __restrict__ bias,
    unsigned short* __restrict__ OUT, int outStride) {
  __shared__ __align__(16) char smem[64 * 66 * 4];
  unsigned short* sA = (unsigned short*)smem;
  float* sC = (float*)smem;
  const int tid = threadIdx.x;
  const int m0 = blockIdx.x * 64;

  {
    int m = tid >> 2, qr = tid & 3;
    int row = m0 + m;
    float a0[16], a1[16];
#pragma unroll
    for (int c = 0; c < 16; ++c) { a0[c] = 0.f; a1[c] = 0.f; }
    if (row < NN) {
      int beg = off[row], end = off[row + 1];
      int e = beg;
      for (; e + 2 <= end; e += 2) {
        int s0 = csr[e], s1 = csr[e + 1];
        const uint4* r0 = (const uint4*)(F + (size_t)s0 * 64) + qr * 2;
        const uint4* r1 = (const uint4*)(F + (size_t)s1 * 64) + qr * 2;
        uint4 p0 = r0[0], p1 = r0[1], q0 = r1[0], q1 = r1[1];
        a0[0] += bflo(p0.x); a0[1] += bfhi(p0.x);
        a0[2] += bflo(p0.y); a0[3] += bfhi(p0.y);
        a0[4] += bflo(p0.z); a0[5] += bfhi(p0.z);
        a0[6] += bflo(p0.w); a0[7] += bfhi(p0.w);
        a0[8] += bflo(p1.x); a0[9] += bfhi(p1.x);
        a0[10] += bflo(p1.y); a0[11] += bfhi(p1.y);
        a0[12] += bflo(p1.z); a0[13] += bfhi(p1.z);
        a0[14] += bflo(p1.w); a0[15] += bfhi(p1.w);
        a1[0] += bflo(q0.x); a1[1] += bfhi(q0.x);
        a1[2] += bflo(q0.y); a1[3] += bfhi(q0.y);
        a1[4] += bflo(q0.z); a1[5] += bfhi(q0.z);
        a1[6] += bflo(q0.w); a1[7] += bfhi(q0.w);
        a1[8] += bflo(q1.x); a1[9] += bfhi(q1.x);
        a1[10] += bflo(q1.y); a1[11] += bfhi(q1.y);
        a1[12] += bflo(q1.z); a1[13] += bfhi(q1.z);
        a1[14] += bflo(q1.w); a1[15] += bfhi(q1.w);
      }
      if (e < end) {
        const uint4* r0 = (const uint4*)(F + (size_t)csr[e] * 64) + qr * 2;
        uint4 p0 = r0[0], p1 = r0[1];
        a0[0] += bflo(p0.x); a0[1] += bfhi(p0.x);
        a0[2] += bflo(p0.y); a0[3] += bfhi(p0.y);
        a0[4] += bflo(p0.z); a0[5] += bfhi(p0.z);
        a0[6] += bflo(p0.w); a0[7] += bfhi(p0.w);
        a0[8] += bflo(p1.x); a0[9] += bfhi(p1.x);
        a0[10] += bflo(p1.y); a0[11] += bfhi(p1.y);
        a0[12] += bflo(p1.z); a0[13] += bfhi(p1.z);
        a0[14] += bflo(p1.w); a0[15] += bfhi(p1.w);
      }
      float iv = inv[row];
#pragma unroll
      for (int c = 0; c < 16; ++c) a0[c] = (a0[c] + a1[c]) * iv;
    }
    int wv = m >> 4, mr = m & 15;
#pragma unroll
    for (int h = 0; h < 2; ++h) {
      int k8 = qr * 2 + h;
      int t = k8 >> 2, kq = k8 & 3;
      uint4 o;
      o.x = packbf2(a0[h * 8 + 0], a0[h * 8 + 1]);
      o.y = packbf2(a0[h * 8 + 2], a0[h * 8 + 3]);
      o.z = packbf2(a0[h * 8 + 4], a0[h * 8 + 5]);
      o.w = packbf2(a0[h * 8 + 6], a0[h * 8 + 7]);
      ((uint4*)sA)[(wv * 4 + t) * 64 + kq * 16 + mr] = o;
    }
  }
#pragma unroll
  for (int l = 0; l < 2; ++l) {
    int c = tid + l * 256;
    int m = c >> 3, j = c & 7;
    int row = m0 + m;
    uint4 v = make_uint4(0, 0, 0, 0);
    if (row < NN) v = ((const uint4*)(F + (size_t)row * 64))[j];
    int k8 = 8 + j, t = k8 >> 2, kq = k8 & 3;
    int wv = m >> 4, mr = m & 15;
    ((uint4*)sA)[(wv * 4 + t) * 64 + kq * 16 + mr] = v;
  }
  __syncthreads();

  const int w = tid >> 6, L = tid & 63;
  const bf16x8* Af = (const bf16x8*)sA;
  const bf16x8* Bf = (const bf16x8*)Wp;
  f32x4 acc[NF];
#pragma unroll
  for (int i = 0; i < NF; ++i)
#pragma unroll
    for (int j = 0; j < 4; ++j) acc[i][j] = 0.f;
#pragma unroll
  for (int t = 0; t < 4; ++t) {
    bf16x8 afr = Af[(w * 4 + t) * 64 + L];
#pragma unroll
    for (int n0 = 0; n0 < NF; ++n0) {
      bf16x8 bfr = Bf[(n0 * 4 + t) * 64 + L];
      acc[n0] = __builtin_amdgcn_mfma_f32_16x16x32_bf16(afr, bfr, acc[n0], 0, 0, 0);
    }
  }

  int rg = L >> 4, cl = L & 15;
#pragma unroll
  for (int half = 0; half < NF / 4; ++half) {
    __syncthreads();
#pragma unroll
    for (int n0 = 0; n0 < 4; ++n0)
#pragma unroll
      for (int r = 0; r < 4; ++r)
        sC[(w * 16 + rg * 4 + r) * 66 + n0 * 16 + cl] = acc[half * 4 + n0][r];
    __syncthreads();
#pragma unroll
    for (int it = 0; it < 2; ++it) {
      int c = tid + it * 256;
      int m = c >> 3, c8 = c & 7;
      int row = m0 + m;
      if (row < NN) {
        float v[8];
#pragma unroll
        for (int j = 0; j < 8; ++j)
          v[j] = fmaxf(sC[m * 66 + c8 * 8 + j] + bias[half * 64 + c8 * 8 + j], 0.f);
        uint4 o;
        o.x = packbf2(v[0], v[1]); o.y = packbf2(v[2], v[3]);
        o.z = packbf2(v[4], v[5]); o.w = packbf2(v[6], v[7]);
        ((uint4*)(OUT + (size_t)row * outStride + half * 64))[c8] = o;
      }
    }
  }
}

// ------------------------------------------------------------ MFMA GEMM -----
// (layer 2: h1 @ wl -> OUT, h1 @ wr -> OUT2)
__global__ __launch_bounds__(256) void k_gemm(
    const unsigned short* __restrict__ S0,
    const unsigned short* __restrict__ Wp,
    const unsigned short* __restrict__ Wp2, unsigned short* __restrict__ OUT2,
    unsigned short* __restrict__ OUT, int M) {
  __shared__ __align__(16) char smem[64 * 66 * 4];
  unsigned short* sA = (unsigned short*)smem;
  float* sC = (float*)smem;
  const int tid = threadIdx.x;
  if (blockIdx.y == 1) { Wp = Wp2; OUT = OUT2; }
  const int m0 = blockIdx.x * 64;

#pragma unroll
  for (int l = 0; l < 4; ++l) {
    int c = tid + l * 256;
    int m = c >> 4, k8 = c & 15;
    int row = m0 + m;
    uint4 v = make_uint4(0, 0, 0, 0);
    if (row < M) v = ((const uint4*)(S0 + (size_t)row * 128))[k8];
    int wv = m >> 4, mr = m & 15, t = k8 >> 2, kq = k8 & 3;
    ((uint4*)sA)[(wv * 4 + t) * 64 + (kq * 16 + mr)] = v;
  }
  __syncthreads();

  const int w = tid >> 6, L = tid & 63;
  f32x4 acc[4];
#pragma unroll
  for (int i = 0; i < 4; ++i)
#pragma unroll
    for (int j = 0; j < 4; ++j) acc[i][j] = 0.f;

  const bf16x8* Af = (const bf16x8*)sA;
  const bf16x8* Bf = (const bf16x8*)Wp;
#pragma unroll
  for (int t = 0; t < 4; ++t) {
    bf16x8 afr = Af[(w * 4 + t) * 64 + L];
#pragma unroll
    for (int n0 = 0; n0 < 4; ++n0) {
      bf16x8 bfr = Bf[(n0 * 4 + t) * 64 + L];
      acc[n0] = __builtin_amdgcn_mfma_f32_16x16x32_bf16(afr, bfr, acc[n0], 0, 0, 0);
    }
  }
  __syncthreads();
  {
    int rg = L >> 4, cl = L & 15;
#pragma unroll
    for (int n0 = 0; n0 < 4; ++n0)
#pragma unroll
      for (int r = 0; r < 4; ++r)
        sC[(w * 16 + rg * 4 + r) * 66 + n0 * 16 + cl] = acc[n0][r];
  }
  __syncthreads();
#pragma unroll
  for (int it = 0; it < 2; ++it) {
    int c = tid + it * 256;
    int m = c >> 3, c8 = c & 7;
    int row = m0 + m;
    if (row < M) {
      float v[8];
#pragma unroll
      for (int j = 0; j < 8; ++j) v[j] = sC[m * 66 + c8 * 8 + j];
      uint4 o;
      o.x = packbf2(v[0], v[1]); o.y = packbf2(v[2], v[3]);
      o.z = packbf2(v[4], v[5]); o.w = packbf2(v[6], v[7]);
      ((uint4*)(OUT + (size_t)row * 64))[c8] = o;
    }
  }
}

// ----------------------------------------------- fused mean-pool + MLP ------
__global__ __launch_bounds__(64) void k_poolmlp(
    const unsigned short* __restrict__ H, const int* __restrict__ gstart,
    const float* __restrict__ w1, const float* __restrict__ b1,
    const float* __restrict__ w2, const float* __restrict__ b2,
    const float* __restrict__ w3, const float* __restrict__ b3,
    const float* __restrict__ w4, const float* __restrict__ b4,
    float* __restrict__ out) {
  __shared__ float sg[64], s1[64], s2[32], s3[32];
  int g = blockIdx.x, t = threadIdx.x;
  int beg = gstart[g], end = gstart[g + 1];
  float acc = 0.0f;
#pragma unroll 4
  for (int n = beg; n < end; ++n) acc += bfs(H[(size_t)n * 64 + t]);
  float cnt = fmaxf((float)(end - beg), 1.0f);
  sg[t] = acc / cnt;
  __syncthreads();
  acc = b1[t];
  for (int k = 0; k < 64; ++k) acc += sg[k] * w1[k * 64 + t];
  s1[t] = fmaxf(acc, 0.0f);
  __syncthreads();
  if (t < 32) {
    acc = b2[t];
    for (int k = 0; k < 64; ++k) acc += s1[k] * w2[k * 32 + t];
    s2[t] = fmaxf(acc, 0.0f);
  }
  __syncthreads();
  if (t < 32) {
    acc = b3[t];
    for (int k = 0; k < 32; ++k) acc += s2[k] * w3[k * 32 + t];
    s3[t] = fmaxf(acc, 0.0f);
  }
  __syncthreads();
  if (t == 0) {
    acc = b4[0];
    for (int k = 0; k < 32; ++k) acc += s3[k] * w4[k];
    out[g] = acc;
  }
}

// ---------------------------------------------------------------- launch ----
extern "C" void kernel_launch(void* const* d_in, const int* in_sizes, int n_in,
                              void* d_out, int out_size, void* d_ws,
                              size_t ws_size, hipStream_t stream) {
  const float* x     = (const float*)d_in[0];
  const int*   ei    = (const int*)d_in[1];
  const int*   batch = (const int*)d_in[2];
  const int* src = ei;
  const int* dst = ei + NE;

  const float* c1_wl = (const float*)d_in[3];
  const float* c1_bl = (const float*)d_in[4];
  const float* c1_wr = (const float*)d_in[5];
  const float* c2_wl = (const float*)d_in[6];
  const float* c2_bl = (const float*)d_in[7];
  const float* c2_wr = (const float*)d_in[8];
  const float* c3_wl = (const float*)d_in[9];
  const float* c3_bl = (const float*)d_in[10];
  const float* c3_wr = (const float*)d_in[11];
  const float* c4_wl = (const float*)d_in[12];
  const float* c4_bl = (const float*)d_in[13];
  const float* c4_wr = (const float*)d_in[14];
  const float* l1w = (const float*)d_in[15];
  const float* l1b = (const float*)d_in[16];
  const float* l2w = (const float*)d_in[17];
  const float* l2b = (const float*)d_in[18];
  const float* l3w = (const float*)d_in[19];
  const float* l3b = (const float*)d_in[20];
  const float* l4w = (const float*)d_in[21];
  const float* l4b = (const float*)d_in[22];

  // ---- workspace carve-up
  char* wsb = (char*)d_ws;
  float* inv = (float*)wsb;                                   // NN fp32
  unsigned short* xb  = (unsigned short*)(wsb + (size_t)NN * 4);
  unsigned short* B1  = xb + (size_t)NN * 64;    // h2 / h4
  unsigned short* B2  = B1 + (size_t)NN * 64;    // h1 (NN x 128)
  unsigned short* B3  = B2 + (size_t)NN * 128;   // U / h3
  unsigned short* B4  = B3 + (size_t)NN * 64;    // V
  unsigned short* ZZ  = B4 + (size_t)NN * 64;    // x@wr + bias (NN x 128)
  unsigned short* pL1  = ZZ + (size_t)NN * 128;  // 128x128 pack
  unsigned short* pL2a = pL1 + 128 * 128;
  unsigned short* pL2b = pL2a + 128 * 64;
  unsigned short* pL3  = pL2b + 128 * 64;
  unsigned short* pL4  = pL3 + 128 * 64;
  unsigned short* pLZ  = pL4 + 128 * 64;         // 64x128 pack (Z-gemm)
  int* cnt    = (int*)(pLZ + 64 * 128);          // NN*CPAD
  int* off    = cnt + (size_t)NN * CPAD;         // NN+1
  int* bsum   = off + NN + 1;                    // 512
  int* gstart = bsum + 512;                      // NG+1
  int* csr    = gstart + NG + 1 + 2;             // NE
  int* rank   = csr + NE;                        // NE

  const int gE  = (NE + 255) / 256;   // 6250
  const int gN8 = NN * 8 / 256;       // 3125
  const int gM  = (NN + 63) / 64;     // 1563
  const int gN  = NBLK_SCAN;          // 391

  hipMemsetAsync(cnt, 0, (size_t)NN * CPAD * 4, stream);

  // ---- Z-gemm weight pack (must precede k_setup which reads it)
  k_prepz<<<32, 256, 0, stream>>>(c1_wr, pLZ);

  // ---- merged setup: count (even blocks) interleaved 1:1 with
  //      Z-gemm/cvt/bounds/prep (odd blocks) so compute hides under atomics
  k_setup<<<GB_SETUP, 256, 0, stream>>>(dst, cnt, rank, x, xb, batch, gstart,
                                        pLZ, c1_bl, ZZ,
                                        c1_wl, c1_wr, c2_wl, c2_wr,
                                        c3_wl, c3_wr, c4_wl, c4_wr,
                                        pL1, pL2a, pL2b, pL3, pL4);
  k_scan1<<<gN, 256, 0, stream>>>(cnt, off, bsum);
  k_scan23<<<gN, 256, 0, stream>>>(off, bsum, cnt, inv);
  k_fill<<<dim3(gE, NPART), 256, 0, stream>>>(src, dst, off, rank, csr);

  // ---- layer 1 (fused, K=64): B2(h1) = relu(agg(x)@WL + ZZ)
  k_fgemm1<<<gM, 256, 0, stream>>>(xb, csr, off, inv, pL1, ZZ, B2);

  // ---- layer 2: B3 = h1@wl, B4 = h1@wr; B1(h2) = relu(agg(B3) + b + B4)
  k_gemm<<<dim3(gM, 2), 256, 0, stream>>>(B2, pL2a, pL2b, B4, B3, NN);
  k_gather<<<gN8, 256, 0, stream>>>(B3, csr, off, inv, c2_bl, B4, B1);

  // ---- layer 3 (fused): B3(h3) = relu([agg(h2)|h2] @ pL3 + c3_bl)
  k_fgemm<4><<<gM, 256, 0, stream>>>(B1, csr, off, inv, pL3, c3_bl, B3, 64);

  // ---- layer 4 (fused): B1(h4) = relu([agg(h3)|h3] @ pL4 + c4_bl)
  k_fgemm<4><<<gM, 256, 0, stream>>>(B3, csr, off, inv, pL4, c4_bl, B1, 64);

  // ---- fused pool + MLP
  k_poolmlp<<<NG, 64, 0, stream>>>(B1, gstart, l1w, l1b, l2w, l2b,
                                   l3w, l3b, l4w, l4b, (float*)d_out);
}